// Round 1
// baseline (847.028 us; speedup 1.0000x reference)
//
#include <hip/hip_runtime.h>
#include <cmath>

#define NT 256
#define HID 128

// ---------------- setup kernels ----------------

__global__ void k_zero(int* __restrict__ cnt, int* __restrict__ tc, int N) {
    int i = blockIdx.x * blockDim.x + threadIdx.x;
    if (i < N) cnt[i] = 0;
    if (i < 16) tc[i] = 0;
}

__global__ void k_hist_edge(const int* __restrict__ dst, int* __restrict__ cnt, int E) {
    int e = blockIdx.x * blockDim.x + threadIdx.x;
    if (e < E) atomicAdd(&cnt[dst[e]], 1);
}

__global__ void k_hist_type(const int* __restrict__ type, int* __restrict__ tc, int N) {
    int i = blockIdx.x * blockDim.x + threadIdx.x;
    int t = (i < N) ? type[i] : -1;
    int lane = threadIdx.x & 63;
    #pragma unroll
    for (int tt = 0; tt < 4; ++tt) {
        unsigned long long m = __ballot(t == tt);
        if (lane == 0 && m) atomicAdd(&tc[tt], __popcll(m));
    }
}

// block-sum of 1024 cnt entries -> partials[block]
__global__ void k_scan1(const int* __restrict__ cnt, int* __restrict__ partials, int N) {
    __shared__ int sdata[NT];
    int base = blockIdx.x * 1024;
    int tid = threadIdx.x;
    int s = 0;
    #pragma unroll
    for (int k = 0; k < 4; ++k) {
        int idx = base + tid * 4 + k;
        if (idx < N) s += cnt[idx];
    }
    sdata[tid] = s;
    __syncthreads();
    for (int off = NT / 2; off > 0; off >>= 1) {
        if (tid < off) sdata[tid] += sdata[tid + off];
        __syncthreads();
    }
    if (tid == 0) partials[blockIdx.x] = sdata[0];
}

// serial scan of partials (nb ~ 98) + type offsets; tiny
__global__ void k_scan2(int* __restrict__ partials, int nb, int* __restrict__ tc,
                        int* __restrict__ rowptr, int N) {
    int run = 0;
    for (int b = 0; b < nb; ++b) { int v = partials[b]; partials[b] = run; run += v; }
    rowptr[N] = run;
    int r2 = 0;
    for (int t = 0; t < 4; ++t) { int c = tc[t]; tc[4 + t] = r2; tc[8 + t] = r2; r2 += c; }
}

// block-local exclusive scan + add partial prefix -> rowptr/cursor/dinv
__global__ void k_scan3(const int* __restrict__ cnt, const int* __restrict__ partials,
                        int* __restrict__ rowptr, int* __restrict__ cursor,
                        float* __restrict__ dinv, int N) {
    __shared__ int sdata[NT];
    int base = blockIdx.x * 1024;
    int tid = threadIdx.x;
    int a[4];
    int s = 0;
    #pragma unroll
    for (int k = 0; k < 4; ++k) {
        int idx = base + tid * 4 + k;
        a[k] = (idx < N) ? cnt[idx] : 0;
        s += a[k];
    }
    sdata[tid] = s;
    __syncthreads();
    for (int off = 1; off < NT; off <<= 1) {
        int v = (tid >= off) ? sdata[tid - off] : 0;
        __syncthreads();
        sdata[tid] += v;
        __syncthreads();
    }
    int excl = sdata[tid] - s;
    int run = partials[blockIdx.x] + excl;
    #pragma unroll
    for (int k = 0; k < 4; ++k) {
        int idx = base + tid * 4 + k;
        if (idx < N) {
            rowptr[idx] = run;
            cursor[idx] = run;
            dinv[idx] = rsqrtf((float)(a[k] + 1));
            run += a[k];
        }
    }
}

// bucket node ids by type (wave-aggregated atomics)
__global__ void k_scatter(const int* __restrict__ type, int* __restrict__ tc,
                          int* __restrict__ order, int N) {
    int i = blockIdx.x * blockDim.x + threadIdx.x;
    int lane = threadIdx.x & 63;
    int t = (i < N) ? type[i] : -1;
    unsigned long long below = (1ull << lane) - 1ull;
    int pos = 0;
    #pragma unroll
    for (int tt = 0; tt < 4; ++tt) {
        unsigned long long m = __ballot(t == tt);
        if (!m) continue;
        int leader = __ffsll((unsigned long long)m) - 1;
        int base = 0;
        if (lane == leader) base = atomicAdd(&tc[8 + tt], __popcll(m));
        base = __shfl(base, leader, 64);
        if (t == tt) pos = base + __popcll(m & below);
    }
    if (i < N) order[pos] = i;
}

__global__ void k_fill(const int* __restrict__ src, const int* __restrict__ dst,
                       int* __restrict__ cursor, int* __restrict__ col, int E) {
    int e = blockIdx.x * blockDim.x + threadIdx.x;
    if (e < E) {
        int p = atomicAdd(&cursor[dst[e]], 1);
        col[p] = src[e];
    }
}

// ---------------- main kernels ----------------

// res[n] = tanh(x[n] @ W[type[n]] + b[type[n]]); nodes processed in type-bucketed order
__global__ __launch_bounds__(NT) void k_adapt(const float* __restrict__ X,
                                              const int* __restrict__ type,
                                              const int* __restrict__ order,
                                              const float* __restrict__ AW,
                                              const float* __restrict__ Ab,
                                              float* __restrict__ out, int N) {
    int chunk = blockIdx.x & 1;
    int i = (blockIdx.x >> 1) * NT + threadIdx.x;
    if (i >= N) return;
    int n = order[i];
    int t = type[n];
    const float4* xr = (const float4*)(X + (size_t)n * HID);
    const float* Wt = AW + (size_t)t * HID * HID + chunk * 64;
    float acc[64];
    #pragma unroll
    for (int h = 0; h < 64; ++h) acc[h] = 0.f;
    for (int d4 = 0; d4 < 32; ++d4) {
        float4 xv = xr[d4];
        #pragma unroll
        for (int j = 0; j < 4; ++j) {
            float xd = (j == 0) ? xv.x : (j == 1) ? xv.y : (j == 2) ? xv.z : xv.w;
            const float4* w4 = (const float4*)(Wt + (size_t)(d4 * 4 + j) * HID);
            #pragma unroll
            for (int k = 0; k < 16; ++k) {
                float4 w = w4[k];
                acc[4 * k + 0] += xd * w.x;
                acc[4 * k + 1] += xd * w.y;
                acc[4 * k + 2] += xd * w.z;
                acc[4 * k + 3] += xd * w.w;
            }
        }
    }
    const float4* bt = (const float4*)(Ab + t * HID + chunk * 64);
    float4* orow = (float4*)(out + (size_t)n * HID + chunk * 64);
    #pragma unroll
    for (int k = 0; k < 16; ++k) {
        float4 b = bt[k];
        float4 v;
        v.x = tanhf(acc[4 * k + 0] + b.x);
        v.y = tanhf(acc[4 * k + 1] + b.y);
        v.z = tanhf(acc[4 * k + 2] + b.z);
        v.w = tanhf(acc[4 * k + 3] + b.w);
        orow[k] = v;
    }
}

// Y[n] = (X[n] @ W) * dinv[n]   (W uniform -> scalar loads)
__global__ __launch_bounds__(NT) void k_mm(const float* __restrict__ X,
                                           const float* __restrict__ W,
                                           const float* __restrict__ dinv,
                                           float* __restrict__ Y, int N) {
    int chunk = blockIdx.x & 1;
    int n = (blockIdx.x >> 1) * NT + threadIdx.x;
    if (n >= N) return;
    const float4* xr = (const float4*)(X + (size_t)n * HID);
    const float* Wc = W + chunk * 64;
    float acc[64];
    #pragma unroll
    for (int h = 0; h < 64; ++h) acc[h] = 0.f;
    for (int d4 = 0; d4 < 32; ++d4) {
        float4 xv = xr[d4];
        #pragma unroll
        for (int j = 0; j < 4; ++j) {
            float xd = (j == 0) ? xv.x : (j == 1) ? xv.y : (j == 2) ? xv.z : xv.w;
            const float4* w4 = (const float4*)(Wc + (size_t)(d4 * 4 + j) * HID);
            #pragma unroll
            for (int k = 0; k < 16; ++k) {
                float4 w = w4[k];
                acc[4 * k + 0] += xd * w.x;
                acc[4 * k + 1] += xd * w.y;
                acc[4 * k + 2] += xd * w.z;
                acc[4 * k + 3] += xd * w.w;
            }
        }
    }
    float s = dinv[n];
    float4* yo = (float4*)(Y + (size_t)n * HID + chunk * 64);
    #pragma unroll
    for (int k = 0; k < 16; ++k) {
        float4 v;
        v.x = acc[4 * k + 0] * s;
        v.y = acc[4 * k + 1] * s;
        v.z = acc[4 * k + 2] * s;
        v.w = acc[4 * k + 3] * s;
        yo[k] = v;
    }
}

// out[n] = dinv[n] * (sum_{e in row n} Y[col[e]] + Y[n]) + bias ; 1 wave per node
__global__ __launch_bounds__(NT) void k_agg(const float* __restrict__ Y,
                                            const int* __restrict__ rowptr,
                                            const int* __restrict__ col,
                                            const float* __restrict__ dinv,
                                            const float* __restrict__ bias,
                                            float* __restrict__ out, int N) {
    int gw = (int)((blockIdx.x * (unsigned)blockDim.x + threadIdx.x) >> 6);
    int lane = threadIdx.x & 63;
    if (gw >= N) return;
    const float2* Yp = (const float2*)Y;
    size_t self = (size_t)gw * 64 + lane;
    float2 acc = Yp[self];
    int beg = rowptr[gw], end = rowptr[gw + 1];
    for (int e = beg; e < end; ++e) {
        int s = col[e];
        float2 v = Yp[(size_t)s * 64 + lane];
        acc.x += v.x;
        acc.y += v.y;
    }
    float dn = dinv[gw];
    float2 bb = ((const float2*)bias)[lane];
    float2 r;
    r.x = acc.x * dn + bb.x;
    r.y = acc.y * dn + bb.y;
    ((float2*)out)[self] = r;
}

// ---------------- launch ----------------

extern "C" void kernel_launch(void* const* d_in, const int* in_sizes, int n_in,
                              void* d_out, int out_size, void* d_ws, size_t ws_size,
                              hipStream_t stream) {
    const float* X = (const float*)d_in[0];
    const int* ntype = (const int*)d_in[1];
    const int* eidx = (const int*)d_in[3];
    const float* AW = (const float*)d_in[5];
    const float* Ab = (const float*)d_in[6];
    const float* W1 = (const float*)d_in[7];
    const float* b1 = (const float*)d_in[8];
    const float* W2 = (const float*)d_in[9];
    const float* b2 = (const float*)d_in[10];

    int N = in_sizes[0] / HID;
    int E = in_sizes[3] / 2;
    const int* esrc = eidx;
    const int* edst = eidx + E;
    float* out = (float*)d_out;

    char* ws = (char*)d_ws;
    size_t off = 0;
    auto carve = [&](size_t bytes) -> void* {
        void* p = ws + off;
        off += (bytes + 255) & ~(size_t)255;
        return p;
    };
    float* Y = (float*)carve((size_t)N * HID * sizeof(float));
    int* cnt = (int*)carve((size_t)N * sizeof(int));
    int* rowptr = (int*)carve((size_t)(N + 1) * sizeof(int));
    int* cursor = (int*)carve((size_t)N * sizeof(int));
    float* dinv = (float*)carve((size_t)N * sizeof(float));
    int* order = (int*)carve((size_t)N * sizeof(int));
    int* col = (int*)carve((size_t)E * sizeof(int));
    int* tc = (int*)carve(16 * sizeof(int));
    int nb = (N + 1023) / 1024;
    int* partials = (int*)carve((size_t)nb * sizeof(int));
    (void)ws_size;
    (void)n_in;
    (void)out_size;

    int gN = (N + NT - 1) / NT;
    int gE = (E + NT - 1) / NT;

    k_zero<<<gN, NT, 0, stream>>>(cnt, tc, N);
    k_hist_edge<<<gE, NT, 0, stream>>>(edst, cnt, E);
    k_hist_type<<<gN, NT, 0, stream>>>(ntype, tc, N);
    k_scan1<<<nb, NT, 0, stream>>>(cnt, partials, N);
    k_scan2<<<1, 1, 0, stream>>>(partials, nb, tc, rowptr, N);
    k_scan3<<<nb, NT, 0, stream>>>(cnt, partials, rowptr, cursor, dinv, N);
    k_scatter<<<gN, NT, 0, stream>>>(ntype, tc, order, N);
    k_fill<<<gE, NT, 0, stream>>>(esrc, edst, cursor, col, E);

    // adapt -> d_out (used as ping buffer)
    k_adapt<<<2 * gN, NT, 0, stream>>>(X, ntype, order, AW, Ab, out, N);
    // layer 1
    k_mm<<<2 * gN, NT, 0, stream>>>(out, W1, dinv, Y, N);
    k_agg<<<(N + 3) / 4, NT, 0, stream>>>(Y, rowptr, col, dinv, b1, out, N);
    // layer 2
    k_mm<<<2 * gN, NT, 0, stream>>>(out, W2, dinv, Y, N);
    k_agg<<<(N + 3) / 4, NT, 0, stream>>>(Y, rowptr, col, dinv, b2, out, N);
}

// Round 2
// 614.083 us; speedup vs baseline: 1.3793x; 1.3793x over previous
//
#include <hip/hip_runtime.h>
#include <cmath>

#define NT 256
#define HID 128

__device__ __forceinline__ float fast_tanh(float x) {
    float cx = fminf(fmaxf(x, -15.f), 15.f);
    float e = __expf(2.f * cx);
    return (e - 1.f) / (e + 1.f);
}

// ---------------- setup kernels ----------------

// grid covers Nord = (gN+4)*256 threads; order initialized to -1 everywhere
__global__ void k_zero(int* __restrict__ cnt, int* __restrict__ tc,
                       int* __restrict__ order, int N) {
    int i = blockIdx.x * blockDim.x + threadIdx.x;
    order[i] = -1;
    if (i < N) cnt[i] = 0;
    if (i < 16) tc[i] = 0;
}

__global__ void k_hist_edge(const int* __restrict__ dst, int* __restrict__ cnt, int E) {
    int e = blockIdx.x * blockDim.x + threadIdx.x;
    if (e < E) atomicAdd(&cnt[dst[e]], 1);
}

__global__ void k_hist_type(const int* __restrict__ type, int* __restrict__ tc, int N) {
    int i = blockIdx.x * blockDim.x + threadIdx.x;
    int t = (i < N) ? type[i] : -1;
    int lane = threadIdx.x & 63;
    #pragma unroll
    for (int tt = 0; tt < 4; ++tt) {
        unsigned long long m = __ballot(t == tt);
        if (lane == 0 && m) atomicAdd(&tc[tt], __popcll(m));
    }
}

// block-sum of 1024 cnt entries -> partials[block]
__global__ void k_scan1(const int* __restrict__ cnt, int* __restrict__ partials, int N) {
    __shared__ int sdata[NT];
    int base = blockIdx.x * 1024;
    int tid = threadIdx.x;
    int s = 0;
    #pragma unroll
    for (int k = 0; k < 4; ++k) {
        int idx = base + tid * 4 + k;
        if (idx < N) s += cnt[idx];
    }
    sdata[tid] = s;
    __syncthreads();
    for (int off = NT / 2; off > 0; off >>= 1) {
        if (tid < off) sdata[tid] += sdata[tid + off];
        __syncthreads();
    }
    if (tid == 0) partials[blockIdx.x] = sdata[0];
}

// serial scan of partials (nb ~ 98) + 256-aligned type bucket starts; tiny
__global__ void k_scan2(int* __restrict__ partials, int nb, int* __restrict__ tc,
                        int* __restrict__ rowptr, int N) {
    int run = 0;
    for (int b = 0; b < nb; ++b) { int v = partials[b]; partials[b] = run; run += v; }
    rowptr[N] = run;
    int r2 = 0;
    for (int t = 0; t < 4; ++t) {
        int c = tc[t];
        tc[4 + t] = r2;
        tc[8 + t] = r2;                       // scatter cursor
        r2 = (r2 + c + 255) & ~255;           // next bucket starts 256-aligned
    }
}

// block-local exclusive scan + add partial prefix -> rowptr/cursor/dinv
__global__ void k_scan3(const int* __restrict__ cnt, const int* __restrict__ partials,
                        int* __restrict__ rowptr, int* __restrict__ cursor,
                        float* __restrict__ dinv, int N) {
    __shared__ int sdata[NT];
    int base = blockIdx.x * 1024;
    int tid = threadIdx.x;
    int a[4];
    int s = 0;
    #pragma unroll
    for (int k = 0; k < 4; ++k) {
        int idx = base + tid * 4 + k;
        a[k] = (idx < N) ? cnt[idx] : 0;
        s += a[k];
    }
    sdata[tid] = s;
    __syncthreads();
    for (int off = 1; off < NT; off <<= 1) {
        int v = (tid >= off) ? sdata[tid - off] : 0;
        __syncthreads();
        sdata[tid] += v;
        __syncthreads();
    }
    int excl = sdata[tid] - s;
    int run = partials[blockIdx.x] + excl;
    #pragma unroll
    for (int k = 0; k < 4; ++k) {
        int idx = base + tid * 4 + k;
        if (idx < N) {
            rowptr[idx] = run;
            cursor[idx] = run;
            dinv[idx] = rsqrtf((float)(a[k] + 1));
            run += a[k];
        }
    }
}

// bucket node ids by type (wave-aggregated atomics)
__global__ void k_scatter(const int* __restrict__ type, int* __restrict__ tc,
                          int* __restrict__ order, int N) {
    int i = blockIdx.x * blockDim.x + threadIdx.x;
    int lane = threadIdx.x & 63;
    int t = (i < N) ? type[i] : -1;
    unsigned long long below = (1ull << lane) - 1ull;
    int pos = 0;
    #pragma unroll
    for (int tt = 0; tt < 4; ++tt) {
        unsigned long long m = __ballot(t == tt);
        if (!m) continue;
        int leader = __ffsll((unsigned long long)m) - 1;
        int base = 0;
        if (lane == leader) base = atomicAdd(&tc[8 + tt], __popcll(m));
        base = __shfl(base, leader, 64);
        if (t == tt) pos = base + __popcll(m & below);
    }
    if (i < N) order[pos] = i;
}

__global__ void k_fill(const int* __restrict__ src, const int* __restrict__ dst,
                       int* __restrict__ cursor, int* __restrict__ col, int E) {
    int e = blockIdx.x * blockDim.x + threadIdx.x;
    if (e < E) {
        int p = atomicAdd(&cursor[dst[e]], 1);
        col[p] = src[e];
    }
}

// ---------------- main kernels ----------------

// res[n] = tanh(x[n] @ W[type[n]] + b[type[n]])
// Blocks are single-type (padded buckets) -> W address wave-uniform -> s_load path.
__global__ __launch_bounds__(NT, 1) void k_adapt(const float* __restrict__ X,
                                                 const int* __restrict__ type,
                                                 const int* __restrict__ order,
                                                 const float* __restrict__ AW,
                                                 const float* __restrict__ Ab,
                                                 float* __restrict__ out) {
    int chunk = blockIdx.x & 1;
    int i = (blockIdx.x >> 1) * NT + threadIdx.x;
    int n = order[i];
    if (n < 0) return;
    int t = __builtin_amdgcn_readfirstlane(type[n]);
    const float4* xr = (const float4*)(X + (size_t)n * HID);
    const float* Wt = AW + (size_t)t * HID * HID + chunk * 64;   // uniform
    float acc[64];
    #pragma unroll
    for (int h = 0; h < 64; ++h) acc[h] = 0.f;
    #pragma unroll 1
    for (int d4 = 0; d4 < 32; ++d4) {
        float4 xv = xr[d4];
        const float* w0 = Wt + (size_t)(d4 * 4) * HID;           // uniform
        #pragma unroll
        for (int h = 0; h < 64; ++h) acc[h] = fmaf(xv.x, w0[h], acc[h]);
        #pragma unroll
        for (int h = 0; h < 64; ++h) acc[h] = fmaf(xv.y, w0[HID + h], acc[h]);
        #pragma unroll
        for (int h = 0; h < 64; ++h) acc[h] = fmaf(xv.z, w0[2 * HID + h], acc[h]);
        #pragma unroll
        for (int h = 0; h < 64; ++h) acc[h] = fmaf(xv.w, w0[3 * HID + h], acc[h]);
    }
    const float* bt = Ab + t * HID + chunk * 64;                 // uniform
    float4* orow = (float4*)(out + (size_t)n * HID + chunk * 64);
    #pragma unroll
    for (int k = 0; k < 16; ++k) {
        float4 v;
        v.x = fast_tanh(acc[4 * k + 0] + bt[4 * k + 0]);
        v.y = fast_tanh(acc[4 * k + 1] + bt[4 * k + 1]);
        v.z = fast_tanh(acc[4 * k + 2] + bt[4 * k + 2]);
        v.w = fast_tanh(acc[4 * k + 3] + bt[4 * k + 3]);
        orow[k] = v;
    }
}

// Y[n] = (X[n] @ W) * dinv[n]   (W fully uniform -> s_load path)
__global__ __launch_bounds__(NT, 1) void k_mm(const float* __restrict__ X,
                                              const float* __restrict__ W,
                                              const float* __restrict__ dinv,
                                              float* __restrict__ Y, int N) {
    int chunk = blockIdx.x & 1;
    int n = (blockIdx.x >> 1) * NT + threadIdx.x;
    if (n >= N) return;
    const float4* xr = (const float4*)(X + (size_t)n * HID);
    const float* Wc = W + chunk * 64;                            // uniform
    float acc[64];
    #pragma unroll
    for (int h = 0; h < 64; ++h) acc[h] = 0.f;
    #pragma unroll 1
    for (int d4 = 0; d4 < 32; ++d4) {
        float4 xv = xr[d4];
        const float* w0 = Wc + (size_t)(d4 * 4) * HID;           // uniform
        #pragma unroll
        for (int h = 0; h < 64; ++h) acc[h] = fmaf(xv.x, w0[h], acc[h]);
        #pragma unroll
        for (int h = 0; h < 64; ++h) acc[h] = fmaf(xv.y, w0[HID + h], acc[h]);
        #pragma unroll
        for (int h = 0; h < 64; ++h) acc[h] = fmaf(xv.z, w0[2 * HID + h], acc[h]);
        #pragma unroll
        for (int h = 0; h < 64; ++h) acc[h] = fmaf(xv.w, w0[3 * HID + h], acc[h]);
    }
    float s = dinv[n];
    float4* yo = (float4*)(Y + (size_t)n * HID + chunk * 64);
    #pragma unroll
    for (int k = 0; k < 16; ++k) {
        float4 v;
        v.x = acc[4 * k + 0] * s;
        v.y = acc[4 * k + 1] * s;
        v.z = acc[4 * k + 2] * s;
        v.w = acc[4 * k + 3] * s;
        yo[k] = v;
    }
}

// out[n] = dinv[n] * (sum_{e in row n} Y[col[e]] + Y[n]) + bias ; 1 wave per node
__global__ __launch_bounds__(NT) void k_agg(const float* __restrict__ Y,
                                            const int* __restrict__ rowptr,
                                            const int* __restrict__ col,
                                            const float* __restrict__ dinv,
                                            const float* __restrict__ bias,
                                            float* __restrict__ out, int N) {
    int gw = (int)((blockIdx.x * (unsigned)blockDim.x + threadIdx.x) >> 6);
    int lane = threadIdx.x & 63;
    if (gw >= N) return;
    const float2* Yp = (const float2*)Y;
    size_t self = (size_t)gw * 64 + lane;
    float2 acc = Yp[self];
    int beg = rowptr[gw], end = rowptr[gw + 1];
    for (int e = beg; e < end; ++e) {
        int s = col[e];
        float2 v = Yp[(size_t)s * 64 + lane];
        acc.x += v.x;
        acc.y += v.y;
    }
    float dn = dinv[gw];
    float2 bb = ((const float2*)bias)[lane];
    float2 r;
    r.x = acc.x * dn + bb.x;
    r.y = acc.y * dn + bb.y;
    ((float2*)out)[self] = r;
}

// ---------------- launch ----------------

extern "C" void kernel_launch(void* const* d_in, const int* in_sizes, int n_in,
                              void* d_out, int out_size, void* d_ws, size_t ws_size,
                              hipStream_t stream) {
    const float* X = (const float*)d_in[0];
    const int* ntype = (const int*)d_in[1];
    const int* eidx = (const int*)d_in[3];
    const float* AW = (const float*)d_in[5];
    const float* Ab = (const float*)d_in[6];
    const float* W1 = (const float*)d_in[7];
    const float* b1 = (const float*)d_in[8];
    const float* W2 = (const float*)d_in[9];
    const float* b2 = (const float*)d_in[10];

    int N = in_sizes[0] / HID;
    int E = in_sizes[3] / 2;
    const int* esrc = eidx;
    const int* edst = eidx + E;
    float* out = (float*)d_out;

    int gN = (N + NT - 1) / NT;
    int gE = (E + NT - 1) / NT;
    int gA = gN + 4;              // padded bucket blocks (4 types, each start 256-aligned)
    int Nord = gA * NT;

    char* ws = (char*)d_ws;
    size_t off = 0;
    auto carve = [&](size_t bytes) -> void* {
        void* p = ws + off;
        off += (bytes + 255) & ~(size_t)255;
        return p;
    };
    float* Y = (float*)carve((size_t)N * HID * sizeof(float));
    int* cnt = (int*)carve((size_t)N * sizeof(int));
    int* rowptr = (int*)carve((size_t)(N + 1) * sizeof(int));
    int* cursor = (int*)carve((size_t)N * sizeof(int));
    float* dinv = (float*)carve((size_t)N * sizeof(float));
    int* order = (int*)carve((size_t)Nord * sizeof(int));
    int* col = (int*)carve((size_t)E * sizeof(int));
    int* tc = (int*)carve(16 * sizeof(int));
    int nb = (N + 1023) / 1024;
    int* partials = (int*)carve((size_t)nb * sizeof(int));
    (void)ws_size;
    (void)n_in;
    (void)out_size;

    k_zero<<<gA, NT, 0, stream>>>(cnt, tc, order, N);
    k_hist_edge<<<gE, NT, 0, stream>>>(edst, cnt, E);
    k_hist_type<<<gN, NT, 0, stream>>>(ntype, tc, N);
    k_scan1<<<nb, NT, 0, stream>>>(cnt, partials, N);
    k_scan2<<<1, 1, 0, stream>>>(partials, nb, tc, rowptr, N);
    k_scan3<<<nb, NT, 0, stream>>>(cnt, partials, rowptr, cursor, dinv, N);
    k_scatter<<<gN, NT, 0, stream>>>(ntype, tc, order, N);
    k_fill<<<gE, NT, 0, stream>>>(esrc, edst, cursor, col, E);

    // adapt -> d_out (used as ping buffer)
    k_adapt<<<2 * gA, NT, 0, stream>>>(X, ntype, order, AW, Ab, out);
    // layer 1
    k_mm<<<2 * gN, NT, 0, stream>>>(out, W1, dinv, Y, N);
    k_agg<<<(N + 3) / 4, NT, 0, stream>>>(Y, rowptr, col, dinv, b1, out, N);
    // layer 2
    k_mm<<<2 * gN, NT, 0, stream>>>(out, W2, dinv, Y, N);
    k_agg<<<(N + 3) / 4, NT, 0, stream>>>(Y, rowptr, col, dinv, b2, out, N);
}

// Round 3
// 450.505 us; speedup vs baseline: 1.8802x; 1.3631x over previous
//
#include <hip/hip_runtime.h>
#include <hip/hip_bf16.h>
#include <cmath>

#define NT 256
#define HID 128

typedef __attribute__((ext_vector_type(8))) short short8v;   // 8 bf16 = 4 VGPR
typedef __attribute__((ext_vector_type(4))) float f32x4;

__device__ __forceinline__ unsigned short f2bf(float f) {
    __hip_bfloat16 h(f);
    return __builtin_bit_cast(unsigned short, h);
}
__device__ __forceinline__ float bf_lo(unsigned int u) { return __uint_as_float(u << 16); }
__device__ __forceinline__ float bf_hi(unsigned int u) { return __uint_as_float(u & 0xffff0000u); }

__device__ __forceinline__ float fast_tanh(float x) {
    float cx = fminf(fmaxf(x, -15.f), 15.f);
    float e = __expf(2.f * cx);
    return (e - 1.f) / (e + 1.f);
}

#define MFMA16(a, b, c) __builtin_amdgcn_mfma_f32_16x16x32_bf16(a, b, c, 0, 0, 0)

// ---------------- setup kernels ----------------

__global__ void k_zero(int* __restrict__ cnt, int* __restrict__ tc,
                       int* __restrict__ order, int N) {
    int i = blockIdx.x * blockDim.x + threadIdx.x;
    order[i] = -1;
    if (i < N) cnt[i] = 0;
    if (i < 16) tc[i] = 0;
}

__global__ void k_hist_edge(const int* __restrict__ dst, int* __restrict__ cnt, int E) {
    int e = blockIdx.x * blockDim.x + threadIdx.x;
    if (e < E) atomicAdd(&cnt[dst[e]], 1);
}

__global__ void k_hist_type(const int* __restrict__ type, int* __restrict__ tc, int N) {
    int i = blockIdx.x * blockDim.x + threadIdx.x;
    int t = (i < N) ? type[i] : -1;
    int lane = threadIdx.x & 63;
    #pragma unroll
    for (int tt = 0; tt < 4; ++tt) {
        unsigned long long m = __ballot(t == tt);
        if (lane == 0 && m) atomicAdd(&tc[tt], __popcll(m));
    }
}

__global__ void k_scan1(const int* __restrict__ cnt, int* __restrict__ partials, int N) {
    __shared__ int sdata[NT];
    int base = blockIdx.x * 1024;
    int tid = threadIdx.x;
    int s = 0;
    #pragma unroll
    for (int k = 0; k < 4; ++k) {
        int idx = base + tid * 4 + k;
        if (idx < N) s += cnt[idx];
    }
    sdata[tid] = s;
    __syncthreads();
    for (int off = NT / 2; off > 0; off >>= 1) {
        if (tid < off) sdata[tid] += sdata[tid + off];
        __syncthreads();
    }
    if (tid == 0) partials[blockIdx.x] = sdata[0];
}

__global__ void k_scan2(int* __restrict__ partials, int nb, int* __restrict__ tc,
                        int* __restrict__ rowptr, int N) {
    int run = 0;
    for (int b = 0; b < nb; ++b) { int v = partials[b]; partials[b] = run; run += v; }
    rowptr[N] = run;
    int r2 = 0;
    for (int t = 0; t < 4; ++t) {
        int c = tc[t];
        tc[4 + t] = r2;
        tc[8 + t] = r2;                 // scatter cursor
        r2 = (r2 + c + 255) & ~255;     // buckets 256-aligned -> blocks single-type
    }
}

__global__ void k_scan3(const int* __restrict__ cnt, const int* __restrict__ partials,
                        int* __restrict__ rowptr, int* __restrict__ cursor,
                        float* __restrict__ dinv, int N) {
    __shared__ int sdata[NT];
    int base = blockIdx.x * 1024;
    int tid = threadIdx.x;
    int a[4];
    int s = 0;
    #pragma unroll
    for (int k = 0; k < 4; ++k) {
        int idx = base + tid * 4 + k;
        a[k] = (idx < N) ? cnt[idx] : 0;
        s += a[k];
    }
    sdata[tid] = s;
    __syncthreads();
    for (int off = 1; off < NT; off <<= 1) {
        int v = (tid >= off) ? sdata[tid - off] : 0;
        __syncthreads();
        sdata[tid] += v;
        __syncthreads();
    }
    int excl = sdata[tid] - s;
    int run = partials[blockIdx.x] + excl;
    #pragma unroll
    for (int k = 0; k < 4; ++k) {
        int idx = base + tid * 4 + k;
        if (idx < N) {
            rowptr[idx] = run;
            cursor[idx] = run;
            dinv[idx] = rsqrtf((float)(a[k] + 1));
            run += a[k];
        }
    }
}

__global__ void k_scatter(const int* __restrict__ type, int* __restrict__ tc,
                          int* __restrict__ order, int N) {
    int i = blockIdx.x * blockDim.x + threadIdx.x;
    int lane = threadIdx.x & 63;
    int t = (i < N) ? type[i] : -1;
    unsigned long long below = (1ull << lane) - 1ull;
    int pos = 0;
    #pragma unroll
    for (int tt = 0; tt < 4; ++tt) {
        unsigned long long m = __ballot(t == tt);
        if (!m) continue;
        int leader = __ffsll((unsigned long long)m) - 1;
        int base = 0;
        if (lane == leader) base = atomicAdd(&tc[8 + tt], __popcll(m));
        base = __shfl(base, leader, 64);
        if (t == tt) pos = base + __popcll(m & below);
    }
    if (i < N) order[pos] = i;
}

__global__ void k_fill(const int* __restrict__ src, const int* __restrict__ dst,
                       int* __restrict__ cursor, int* __restrict__ col, int E) {
    int e = blockIdx.x * blockDim.x + threadIdx.x;
    if (e < E) {
        int p = atomicAdd(&cursor[dst[e]], 1);
        col[p] = src[e];
    }
}

// convert + transpose weights to bf16: Wt[col][k] = W[k][col]
__global__ void k_prep(const float* __restrict__ AW, const float* __restrict__ W1,
                       const float* __restrict__ W2, unsigned short* __restrict__ AWt,
                       unsigned short* __restrict__ W1t, unsigned short* __restrict__ W2t) {
    int i = blockIdx.x * NT + threadIdx.x;
    if (i < 65536) {
        int t = i >> 14, rem = i & 16383, c = rem >> 7, k = rem & 127;
        AWt[i] = f2bf(AW[t * 16384 + k * 128 + c]);
    } else if (i < 81920) {
        int j = i - 65536, c = j >> 7, k = j & 127;
        W1t[j] = f2bf(W1[k * 128 + c]);
    } else if (i < 98304) {
        int j = i - 81920, c = j >> 7, k = j & 127;
        W2t[j] = f2bf(W2[k * 128 + c]);
    }
}

// ---------------- MFMA matmul kernels ----------------
// Block: 128 rows x 128 cols. 4 waves, each 32 rows (2 rowgroups of 16).
// LDS: Wt staged swizzled (granule-slot ^= row&15), reused for store-transpose.
// mfma_f32_16x16x32_bf16 layouts (m89-verified family):
//   A: lane holds A[lane&15][8*(lane>>4)+j]   B: lane holds B[8*(lane>>4)+j][lane&15]
//   D: col=lane&15, row=4*(lane>>4)+reg

// Y[n] = bf16( (A[n] @ W) * dinv[n] )
__global__ __launch_bounds__(NT) void k_mm(const unsigned short* __restrict__ Ain,
                                           const unsigned short* __restrict__ Wt,
                                           const float* __restrict__ dinv,
                                           unsigned short* __restrict__ Yout, int N) {
    __shared__ unsigned short lds[16384];   // 32 KB
    char* ldsb = (char*)lds;
    const int tid = threadIdx.x;
    const int lane = tid & 63;
    const int w = tid >> 6;
    const int r = lane & 15, g = lane >> 4;

    {   // stage Wt -> LDS (swizzled)
        int row = tid >> 1, half = tid & 1;
        const uint4* src = (const uint4*)(Wt + row * 128 + half * 64);
        #pragma unroll
        for (int j = 0; j < 8; ++j) {
            int gr = half * 8 + j;
            *(uint4*)(ldsb + row * 256 + ((gr ^ (row & 15)) << 4)) = src[j];
        }
    }
    __syncthreads();

    const int rowbase = blockIdx.x * 128 + w * 32;
    f32x4 acc[2][8];
    #pragma unroll
    for (int h = 0; h < 2; ++h)
        #pragma unroll
        for (int c = 0; c < 8; ++c) { acc[h][c][0] = 0.f; acc[h][c][1] = 0.f; acc[h][c][2] = 0.f; acc[h][c][3] = 0.f; }

    #pragma unroll
    for (int s = 0; s < 4; ++s) {
        short8v a[2];
        #pragma unroll
        for (int h = 0; h < 2; ++h) {
            int n = rowbase + h * 16 + r;
            if (n >= N) n = N - 1;   // slop-safe clamp; stores are guarded
            a[h] = *(const short8v*)(Ain + (size_t)n * 128 + s * 32 + g * 8);
        }
        #pragma unroll
        for (int c = 0; c < 8; ++c) {
            int wr = 16 * c + r;
            short8v b = *(const short8v*)(ldsb + wr * 256 + (((s * 4 + g) ^ (wr & 15)) << 4));
            acc[0][c] = MFMA16(a[0], b, acc[0][c]);
            acc[1][c] = MFMA16(a[1], b, acc[1][c]);
        }
    }
    __syncthreads();   // all waves done reading W from LDS

    // scale + stage bf16 tile in LDS (same swizzle)
    #pragma unroll
    for (int h = 0; h < 2; ++h) {
        float dv[4];
        #pragma unroll
        for (int q = 0; q < 4; ++q) {
            int n = rowbase + h * 16 + g * 4 + q;
            dv[q] = (n < N) ? dinv[n] : 0.f;
        }
        #pragma unroll
        for (int c = 0; c < 8; ++c) {
            #pragma unroll
            for (int q = 0; q < 4; ++q) {
                int rr = w * 32 + h * 16 + g * 4 + q;
                int cb = (16 * c + r) * 2;
                *(unsigned short*)(ldsb + rr * 256 + (((cb >> 4) ^ (rr & 15)) << 4) + (cb & 15)) =
                    f2bf(acc[h][c][q] * dv[q]);
            }
        }
    }
    __syncthreads();

    {   // coalesced full-line stores
        int rr = tid >> 1, half = tid & 1;
        int n = blockIdx.x * 128 + rr;
        if (n < N) {
            uint4* dst = (uint4*)(Yout + (size_t)n * 128 + half * 64);
            #pragma unroll
            for (int j = 0; j < 8; ++j) {
                int gr = half * 8 + j;
                dst[j] = *(const uint4*)(ldsb + rr * 256 + ((gr ^ (rr & 15)) << 4));
            }
        }
    }
}

// A0[n] = bf16( tanh(X[n] @ AW[type[n]] + Ab[type[n]]) ), via type-bucketed order
__global__ __launch_bounds__(NT) void k_adapt(const float* __restrict__ X,
                                              const int* __restrict__ type,
                                              const int* __restrict__ order,
                                              const unsigned short* __restrict__ AWt,
                                              const float* __restrict__ Ab,
                                              unsigned short* __restrict__ A0) {
    __shared__ unsigned short lds[16384];
    char* ldsb = (char*)lds;
    const int i0 = blockIdx.x * 128;
    int n0 = order[i0];
    if (n0 < 0) return;          // whole block is padding
    const int tid = threadIdx.x;
    const int lane = tid & 63;
    const int w = tid >> 6;
    const int r = lane & 15, g = lane >> 4;
    const int t = __builtin_amdgcn_readfirstlane(type[n0]);
    const unsigned short* Wt = AWt + t * 16384;

    {   // stage Wt -> LDS
        int row = tid >> 1, half = tid & 1;
        const uint4* src = (const uint4*)(Wt + row * 128 + half * 64);
        #pragma unroll
        for (int j = 0; j < 8; ++j) {
            int gr = half * 8 + j;
            *(uint4*)(ldsb + row * 256 + ((gr ^ (row & 15)) << 4)) = src[j];
        }
    }
    __syncthreads();

    int nidx[2];
    nidx[0] = order[i0 + w * 32 + r];
    nidx[1] = order[i0 + w * 32 + 16 + r];
    float bcol[8];
    #pragma unroll
    for (int c = 0; c < 8; ++c) bcol[c] = Ab[t * 128 + 16 * c + r];

    f32x4 acc[2][8];
    #pragma unroll
    for (int h = 0; h < 2; ++h)
        #pragma unroll
        for (int c = 0; c < 8; ++c) { acc[h][c][0] = 0.f; acc[h][c][1] = 0.f; acc[h][c][2] = 0.f; acc[h][c][3] = 0.f; }

    #pragma unroll
    for (int s = 0; s < 4; ++s) {
        short8v a[2];
        #pragma unroll
        for (int h = 0; h < 2; ++h) {
            union { short8v s8; unsigned int u[4]; } fa;
            int n = nidx[h];
            if (n >= 0) {
                const float4* xp = (const float4*)(X + (size_t)n * 128 + s * 32 + g * 8);
                float4 x0 = xp[0], x1 = xp[1];
                fa.u[0] = ((unsigned)f2bf(x0.y) << 16) | f2bf(x0.x);
                fa.u[1] = ((unsigned)f2bf(x0.w) << 16) | f2bf(x0.z);
                fa.u[2] = ((unsigned)f2bf(x1.y) << 16) | f2bf(x1.x);
                fa.u[3] = ((unsigned)f2bf(x1.w) << 16) | f2bf(x1.z);
            } else {
                fa.u[0] = fa.u[1] = fa.u[2] = fa.u[3] = 0u;
            }
            a[h] = fa.s8;
        }
        #pragma unroll
        for (int c = 0; c < 8; ++c) {
            int wr = 16 * c + r;
            short8v b = *(const short8v*)(ldsb + wr * 256 + (((s * 4 + g) ^ (wr & 15)) << 4));
            acc[0][c] = MFMA16(a[0], b, acc[0][c]);
            acc[1][c] = MFMA16(a[1], b, acc[1][c]);
        }
    }
    __syncthreads();

    // bias + tanh + stage bf16 tile
    #pragma unroll
    for (int h = 0; h < 2; ++h) {
        #pragma unroll
        for (int c = 0; c < 8; ++c) {
            #pragma unroll
            for (int q = 0; q < 4; ++q) {
                int rr = w * 32 + h * 16 + g * 4 + q;
                int cb = (16 * c + r) * 2;
                *(unsigned short*)(ldsb + rr * 256 + (((cb >> 4) ^ (rr & 15)) << 4) + (cb & 15)) =
                    f2bf(fast_tanh(acc[h][c][q] + bcol[c]));
            }
        }
    }
    __syncthreads();

    {   // coalesced stores, scattered rows via order
        int rr = tid >> 1, half = tid & 1;
        int n = order[i0 + rr];
        if (n >= 0) {
            uint4* dst = (uint4*)(A0 + (size_t)n * 128 + half * 64);
            #pragma unroll
            for (int j = 0; j < 8; ++j) {
                int gr = half * 8 + j;
                dst[j] = *(const uint4*)(ldsb + rr * 256 + ((gr ^ (rr & 15)) << 4));
            }
        }
    }
}

// ---------------- aggregation (bf16 in) ----------------

__global__ __launch_bounds__(NT) void k_agg_bb(const unsigned short* __restrict__ Y,
                                               const int* __restrict__ rowptr,
                                               const int* __restrict__ col,
                                               const float* __restrict__ dinv,
                                               const float* __restrict__ bias,
                                               unsigned short* __restrict__ out, int N) {
    int gw = (int)((blockIdx.x * (unsigned)blockDim.x + threadIdx.x) >> 6);
    int lane = threadIdx.x & 63;
    if (gw >= N) return;
    const unsigned int* Yw = (const unsigned int*)Y;
    unsigned int u = Yw[(size_t)gw * 64 + lane];
    float ax = bf_lo(u), ay = bf_hi(u);
    int beg = rowptr[gw], end = rowptr[gw + 1];
    for (int e = beg; e < end; ++e) {
        unsigned int v = Yw[(size_t)col[e] * 64 + lane];
        ax += bf_lo(v);
        ay += bf_hi(v);
    }
    float dn = dinv[gw];
    float2 bb = ((const float2*)bias)[lane];
    float rx = ax * dn + bb.x, ry = ay * dn + bb.y;
    ((unsigned int*)out)[(size_t)gw * 64 + lane] = ((unsigned)f2bf(ry) << 16) | f2bf(rx);
}

__global__ __launch_bounds__(NT) void k_agg_bf(const unsigned short* __restrict__ Y,
                                               const int* __restrict__ rowptr,
                                               const int* __restrict__ col,
                                               const float* __restrict__ dinv,
                                               const float* __restrict__ bias,
                                               float* __restrict__ out, int N) {
    int gw = (int)((blockIdx.x * (unsigned)blockDim.x + threadIdx.x) >> 6);
    int lane = threadIdx.x & 63;
    if (gw >= N) return;
    const unsigned int* Yw = (const unsigned int*)Y;
    unsigned int u = Yw[(size_t)gw * 64 + lane];
    float ax = bf_lo(u), ay = bf_hi(u);
    int beg = rowptr[gw], end = rowptr[gw + 1];
    for (int e = beg; e < end; ++e) {
        unsigned int v = Yw[(size_t)col[e] * 64 + lane];
        ax += bf_lo(v);
        ay += bf_hi(v);
    }
    float dn = dinv[gw];
    float2 bb = ((const float2*)bias)[lane];
    float2 rv;
    rv.x = ax * dn + bb.x;
    rv.y = ay * dn + bb.y;
    ((float2*)out)[(size_t)gw * 64 + lane] = rv;
}

// ---------------- launch ----------------

extern "C" void kernel_launch(void* const* d_in, const int* in_sizes, int n_in,
                              void* d_out, int out_size, void* d_ws, size_t ws_size,
                              hipStream_t stream) {
    const float* X = (const float*)d_in[0];
    const int* ntype = (const int*)d_in[1];
    const int* eidx = (const int*)d_in[3];
    const float* AW = (const float*)d_in[5];
    const float* Ab = (const float*)d_in[6];
    const float* W1 = (const float*)d_in[7];
    const float* b1 = (const float*)d_in[8];
    const float* W2 = (const float*)d_in[9];
    const float* b2 = (const float*)d_in[10];

    int N = in_sizes[0] / HID;
    int E = in_sizes[3] / 2;
    const int* esrc = eidx;
    const int* edst = eidx + E;
    float* out = (float*)d_out;

    int gN = (N + NT - 1) / NT;
    int gE = (E + NT - 1) / NT;
    int gA = gN + 4;                 // padded bucket blocks (256-aligned starts)
    int Nord = gA * NT;

    char* ws = (char*)d_ws;
    size_t off = 0;
    auto carve = [&](size_t bytes) -> void* {
        void* p = ws + off;
        off += (bytes + 255) & ~(size_t)255;
        return p;
    };
    unsigned short* A0 = (unsigned short*)carve((size_t)N * HID * 2);   // bf16 acts (adapt out, agg1 out)
    unsigned short* Yb = (unsigned short*)carve((size_t)N * HID * 2);   // bf16 mm out
    unsigned short* AWt = (unsigned short*)carve(4 * 16384 * 2);
    unsigned short* W1t = (unsigned short*)carve(16384 * 2);
    unsigned short* W2t = (unsigned short*)carve(16384 * 2);
    int* cnt = (int*)carve((size_t)N * sizeof(int));
    int* rowptr = (int*)carve((size_t)(N + 1) * sizeof(int));
    int* cursor = (int*)carve((size_t)N * sizeof(int));
    float* dinv = (float*)carve((size_t)N * sizeof(float));
    int* order = (int*)carve((size_t)Nord * sizeof(int));
    int* col = (int*)carve((size_t)E * sizeof(int));
    int* tc = (int*)carve(16 * sizeof(int));
    int nb = (N + 1023) / 1024;
    int* partials = (int*)carve((size_t)nb * sizeof(int));
    (void)ws_size;
    (void)n_in;
    (void)out_size;

    k_zero<<<gA, NT, 0, stream>>>(cnt, tc, order, N);
    k_hist_edge<<<gE, NT, 0, stream>>>(edst, cnt, E);
    k_hist_type<<<gN, NT, 0, stream>>>(ntype, tc, N);
    k_prep<<<384, NT, 0, stream>>>(AW, W1, W2, AWt, W1t, W2t);
    k_scan1<<<nb, NT, 0, stream>>>(cnt, partials, N);
    k_scan2<<<1, 1, 0, stream>>>(partials, nb, tc, rowptr, N);
    k_scan3<<<nb, NT, 0, stream>>>(cnt, partials, rowptr, cursor, dinv, N);
    k_scatter<<<gN, NT, 0, stream>>>(ntype, tc, order, N);
    k_fill<<<gE, NT, 0, stream>>>(esrc, edst, cursor, col, E);

    int bMM = (N + 127) / 128;
    int bAD = 2 * gA;                // Nord / 128

    k_adapt<<<bAD, NT, 0, stream>>>(X, ntype, order, AWt, Ab, A0);
    // layer 1
    k_mm<<<bMM, NT, 0, stream>>>(A0, W1t, dinv, Yb, N);
    k_agg_bb<<<(N + 3) / 4, NT, 0, stream>>>(Yb, rowptr, col, dinv, b1, A0, N);
    // layer 2
    k_mm<<<bMM, NT, 0, stream>>>(A0, W2t, dinv, Yb, N);
    k_agg_bf<<<(N + 3) / 4, NT, 0, stream>>>(Yb, rowptr, col, dinv, b2, out, N);
}

// Round 4
// 304.624 us; speedup vs baseline: 2.7806x; 1.4789x over previous
//
#include <hip/hip_runtime.h>
#include <hip/hip_bf16.h>
#include <cmath>

#define NT 256
#define HID 128

typedef __attribute__((ext_vector_type(8))) short short8v;   // 8 bf16 = 4 VGPR
typedef __attribute__((ext_vector_type(4))) float f32x4;

__device__ __forceinline__ unsigned short f2bf(float f) {
    __hip_bfloat16 h(f);
    return __builtin_bit_cast(unsigned short, h);
}
__device__ __forceinline__ float bf_lo(unsigned int u) { return __uint_as_float(u << 16); }
__device__ __forceinline__ float bf_hi(unsigned int u) { return __uint_as_float(u & 0xffff0000u); }

__device__ __forceinline__ float fast_tanh(float x) {
    float cx = fminf(fmaxf(x, -15.f), 15.f);
    float e = __expf(2.f * cx);
    return (e - 1.f) / (e + 1.f);
}

#define MFMA16(a, b, c) __builtin_amdgcn_mfma_f32_16x16x32_bf16(a, b, c, 0, 0, 0)

// ---------------- setup kernels ----------------

__global__ void k_zero(int* __restrict__ cnt, int* __restrict__ order, int N) {
    int i = blockIdx.x * blockDim.x + threadIdx.x;
    order[i] = -1;
    if (i < N) cnt[i] = 0;
}

__global__ void k_hist_edge(const int* __restrict__ dst, int* __restrict__ cnt, int E) {
    int e = blockIdx.x * blockDim.x + threadIdx.x;
    if (e < E) atomicAdd(&cnt[dst[e]], 1);
}

// per-block type histogram -> blkT[t][b]  (no global atomics)
__global__ void k_hist_type(const int* __restrict__ type, int* __restrict__ blkT,
                            int nb2, int N) {
    __shared__ int h[4];
    int tid = threadIdx.x;
    if (tid < 4) h[tid] = 0;
    __syncthreads();
    int i = blockIdx.x * NT + tid;
    int t = (i < N) ? type[i] : -1;
    int lane = tid & 63;
    #pragma unroll
    for (int tt = 0; tt < 4; ++tt) {
        unsigned long long m = __ballot(t == tt);
        if (lane == 0 && m) atomicAdd(&h[tt], __popcll(m));   // LDS atomic only
    }
    __syncthreads();
    if (tid < 4) blkT[tid * nb2 + blockIdx.x] = h[tid];
}

// block-sum of 1024 cnt entries -> partials[block]
__global__ void k_scan1(const int* __restrict__ cnt, int* __restrict__ partials, int N) {
    __shared__ int sdata[NT];
    int base = blockIdx.x * 1024;
    int tid = threadIdx.x;
    int s = 0;
    #pragma unroll
    for (int k = 0; k < 4; ++k) {
        int idx = base + tid * 4 + k;
        if (idx < N) s += cnt[idx];
    }
    sdata[tid] = s;
    __syncthreads();
    for (int off = NT / 2; off > 0; off >>= 1) {
        if (tid < off) sdata[tid] += sdata[tid + off];
        __syncthreads();
    }
    if (tid == 0) partials[blockIdx.x] = sdata[0];
}

// one block: parallel scan of partials (nb<=512) AND per-type scans of blkT (nb2<=512)
__global__ void k_scanmeta(int* __restrict__ partials, int nb,
                           const int* __restrict__ blkT, int* __restrict__ blkBase,
                           int nb2, int* __restrict__ rowptr, int N) {
    __shared__ int s[NT];
    __shared__ int carry;
    int tid = threadIdx.x;

    // ---- scan partials (2 elems/thread) ----
    int v0 = (tid * 2 < nb) ? partials[tid * 2] : 0;
    int v1 = (tid * 2 + 1 < nb) ? partials[tid * 2 + 1] : 0;
    int ts = v0 + v1;
    s[tid] = ts;
    __syncthreads();
    for (int off = 1; off < NT; off <<= 1) {
        int x = (tid >= off) ? s[tid - off] : 0;
        __syncthreads();
        s[tid] += x;
        __syncthreads();
    }
    int excl = s[tid] - ts;
    if (tid * 2 < nb) partials[tid * 2] = excl;
    if (tid * 2 + 1 < nb) partials[tid * 2 + 1] = excl + v0;
    if (tid == NT - 1) rowptr[N] = s[NT - 1];
    __syncthreads();

    // ---- per-type block-base scans, buckets 256-aligned ----
    if (tid == 0) carry = 0;
    __syncthreads();
    for (int t = 0; t < 4; ++t) {
        int w0 = (tid * 2 < nb2) ? blkT[t * nb2 + tid * 2] : 0;
        int w1 = (tid * 2 + 1 < nb2) ? blkT[t * nb2 + tid * 2 + 1] : 0;
        int tw = w0 + w1;
        s[tid] = tw;
        __syncthreads();
        for (int off = 1; off < NT; off <<= 1) {
            int x = (tid >= off) ? s[tid - off] : 0;
            __syncthreads();
            s[tid] += x;
            __syncthreads();
        }
        int ex = s[tid] - tw;
        int base = carry;
        if (tid * 2 < nb2) blkBase[t * nb2 + tid * 2] = base + ex;
        if (tid * 2 + 1 < nb2) blkBase[t * nb2 + tid * 2 + 1] = base + ex + w0;
        __syncthreads();
        if (tid == NT - 1) carry = (base + s[NT - 1] + 255) & ~255;
        __syncthreads();
    }
}

// block-local exclusive scan + add partial prefix -> rowptr/cursor/dinv
__global__ void k_scan3(const int* __restrict__ cnt, const int* __restrict__ partials,
                        int* __restrict__ rowptr, int* __restrict__ cursor,
                        float* __restrict__ dinv, int N) {
    __shared__ int sdata[NT];
    int base = blockIdx.x * 1024;
    int tid = threadIdx.x;
    int a[4];
    int s = 0;
    #pragma unroll
    for (int k = 0; k < 4; ++k) {
        int idx = base + tid * 4 + k;
        a[k] = (idx < N) ? cnt[idx] : 0;
        s += a[k];
    }
    sdata[tid] = s;
    __syncthreads();
    for (int off = 1; off < NT; off <<= 1) {
        int v = (tid >= off) ? sdata[tid - off] : 0;
        __syncthreads();
        sdata[tid] += v;
        __syncthreads();
    }
    int excl = sdata[tid] - s;
    int run = partials[blockIdx.x] + excl;
    #pragma unroll
    for (int k = 0; k < 4; ++k) {
        int idx = base + tid * 4 + k;
        if (idx < N) {
            rowptr[idx] = run;
            cursor[idx] = run;
            dinv[idx] = rsqrtf((float)(a[k] + 1));
            run += a[k];
        }
    }
}

// deterministic, atomic-free type-bucketing scatter
__global__ void k_scatter(const int* __restrict__ type, const int* __restrict__ blkBase,
                          int nb2, int* __restrict__ order, int N) {
    __shared__ int wcnt[4][4];   // [wave][type]
    int tid = threadIdx.x, lane = tid & 63, w = tid >> 6;
    int i = blockIdx.x * NT + tid;
    int t = (i < N) ? type[i] : -1;
    unsigned long long below = (1ull << lane) - 1ull;
    unsigned long long mym = 0;
    #pragma unroll
    for (int tt = 0; tt < 4; ++tt) {
        unsigned long long m = __ballot(t == tt);
        if (lane == 0) wcnt[w][tt] = __popcll(m);
        if (t == tt) mym = m;
    }
    __syncthreads();
    if (t >= 0) {
        int off = 0;
        #pragma unroll
        for (int w2 = 0; w2 < 4; ++w2)
            if (w2 < w) off += wcnt[w2][t];
        int pos = blkBase[t * nb2 + blockIdx.x] + off + __popcll(mym & below);
        order[pos] = i;
    }
}

__global__ void k_fill(const int* __restrict__ src, const int* __restrict__ dst,
                       int* __restrict__ cursor, int* __restrict__ col, int E) {
    int e = blockIdx.x * blockDim.x + threadIdx.x;
    if (e < E) {
        int p = atomicAdd(&cursor[dst[e]], 1);
        col[p] = src[e];
    }
}

// convert + transpose weights to bf16: Wt[col][k] = W[k][col]
__global__ void k_prep(const float* __restrict__ AW, const float* __restrict__ W1,
                       const float* __restrict__ W2, unsigned short* __restrict__ AWt,
                       unsigned short* __restrict__ W1t, unsigned short* __restrict__ W2t) {
    int i = blockIdx.x * NT + threadIdx.x;
    if (i < 65536) {
        int t = i >> 14, rem = i & 16383, c = rem >> 7, k = rem & 127;
        AWt[i] = f2bf(AW[t * 16384 + k * 128 + c]);
    } else if (i < 81920) {
        int j = i - 65536, c = j >> 7, k = j & 127;
        W1t[j] = f2bf(W1[k * 128 + c]);
    } else if (i < 98304) {
        int j = i - 81920, c = j >> 7, k = j & 127;
        W2t[j] = f2bf(W2[k * 128 + c]);
    }
}

// ---------------- MFMA matmul kernels ----------------
// Block: 128 rows x 128 cols. 4 waves, each 32 rows (2 rowgroups of 16).
// LDS: Wt staged swizzled (granule-slot ^= row&15), reused for store-transpose.
// mfma_f32_16x16x32_bf16 layouts (m89-verified family):
//   A: lane holds A[lane&15][8*(lane>>4)+j]   B: lane holds B[8*(lane>>4)+j][lane&15]
//   D: col=lane&15, row=4*(lane>>4)+reg

// Y[n] = bf16( (A[n] @ W) * dinv[n] )
__global__ __launch_bounds__(NT) void k_mm(const unsigned short* __restrict__ Ain,
                                           const unsigned short* __restrict__ Wt,
                                           const float* __restrict__ dinv,
                                           unsigned short* __restrict__ Yout, int N) {
    __shared__ unsigned short lds[16384];   // 32 KB
    char* ldsb = (char*)lds;
    const int tid = threadIdx.x;
    const int lane = tid & 63;
    const int w = tid >> 6;
    const int r = lane & 15, g = lane >> 4;

    {   // stage Wt -> LDS (swizzled)
        int row = tid >> 1, half = tid & 1;
        const uint4* src = (const uint4*)(Wt + row * 128 + half * 64);
        #pragma unroll
        for (int j = 0; j < 8; ++j) {
            int gr = half * 8 + j;
            *(uint4*)(ldsb + row * 256 + ((gr ^ (row & 15)) << 4)) = src[j];
        }
    }
    __syncthreads();

    const int rowbase = blockIdx.x * 128 + w * 32;
    f32x4 acc[2][8];
    #pragma unroll
    for (int h = 0; h < 2; ++h)
        #pragma unroll
        for (int c = 0; c < 8; ++c) { acc[h][c][0] = 0.f; acc[h][c][1] = 0.f; acc[h][c][2] = 0.f; acc[h][c][3] = 0.f; }

    #pragma unroll
    for (int s = 0; s < 4; ++s) {
        short8v a[2];
        #pragma unroll
        for (int h = 0; h < 2; ++h) {
            int n = rowbase + h * 16 + r;
            if (n >= N) n = N - 1;   // slop-safe clamp; stores are guarded
            a[h] = *(const short8v*)(Ain + (size_t)n * 128 + s * 32 + g * 8);
        }
        #pragma unroll
        for (int c = 0; c < 8; ++c) {
            int wr = 16 * c + r;
            short8v b = *(const short8v*)(ldsb + wr * 256 + (((s * 4 + g) ^ (wr & 15)) << 4));
            acc[0][c] = MFMA16(a[0], b, acc[0][c]);
            acc[1][c] = MFMA16(a[1], b, acc[1][c]);
        }
    }
    __syncthreads();   // all waves done reading W from LDS

    // scale + stage bf16 tile in LDS (same swizzle)
    #pragma unroll
    for (int h = 0; h < 2; ++h) {
        float dv[4];
        #pragma unroll
        for (int q = 0; q < 4; ++q) {
            int n = rowbase + h * 16 + g * 4 + q;
            dv[q] = (n < N) ? dinv[n] : 0.f;
        }
        #pragma unroll
        for (int c = 0; c < 8; ++c) {
            #pragma unroll
            for (int q = 0; q < 4; ++q) {
                int rr = w * 32 + h * 16 + g * 4 + q;
                int cb = (16 * c + r) * 2;
                *(unsigned short*)(ldsb + rr * 256 + (((cb >> 4) ^ (rr & 15)) << 4) + (cb & 15)) =
                    f2bf(acc[h][c][q] * dv[q]);
            }
        }
    }
    __syncthreads();

    {   // coalesced full-line stores
        int rr = tid >> 1, half = tid & 1;
        int n = blockIdx.x * 128 + rr;
        if (n < N) {
            uint4* dst = (uint4*)(Yout + (size_t)n * 128 + half * 64);
            #pragma unroll
            for (int j = 0; j < 8; ++j) {
                int gr = half * 8 + j;
                dst[j] = *(const uint4*)(ldsb + rr * 256 + ((gr ^ (rr & 15)) << 4));
            }
        }
    }
}

// A0[n] = bf16( tanh(X[n] @ AW[type[n]] + Ab[type[n]]) ), via type-bucketed order
__global__ __launch_bounds__(NT) void k_adapt(const float* __restrict__ X,
                                              const int* __restrict__ type,
                                              const int* __restrict__ order,
                                              const unsigned short* __restrict__ AWt,
                                              const float* __restrict__ Ab,
                                              unsigned short* __restrict__ A0) {
    __shared__ unsigned short lds[16384];
    char* ldsb = (char*)lds;
    const int i0 = blockIdx.x * 128;
    int n0 = order[i0];
    if (n0 < 0) return;          // whole block is padding
    const int tid = threadIdx.x;
    const int lane = tid & 63;
    const int w = tid >> 6;
    const int r = lane & 15, g = lane >> 4;
    const int t = __builtin_amdgcn_readfirstlane(type[n0]);
    const unsigned short* Wt = AWt + t * 16384;

    {   // stage Wt -> LDS
        int row = tid >> 1, half = tid & 1;
        const uint4* src = (const uint4*)(Wt + row * 128 + half * 64);
        #pragma unroll
        for (int j = 0; j < 8; ++j) {
            int gr = half * 8 + j;
            *(uint4*)(ldsb + row * 256 + ((gr ^ (row & 15)) << 4)) = src[j];
        }
    }
    __syncthreads();

    int nidx[2];
    nidx[0] = order[i0 + w * 32 + r];
    nidx[1] = order[i0 + w * 32 + 16 + r];
    float bcol[8];
    #pragma unroll
    for (int c = 0; c < 8; ++c) bcol[c] = Ab[t * 128 + 16 * c + r];

    f32x4 acc[2][8];
    #pragma unroll
    for (int h = 0; h < 2; ++h)
        #pragma unroll
        for (int c = 0; c < 8; ++c) { acc[h][c][0] = 0.f; acc[h][c][1] = 0.f; acc[h][c][2] = 0.f; acc[h][c][3] = 0.f; }

    #pragma unroll
    for (int s = 0; s < 4; ++s) {
        short8v a[2];
        #pragma unroll
        for (int h = 0; h < 2; ++h) {
            union { short8v s8; unsigned int u[4]; } fa;
            int n = nidx[h];
            if (n >= 0) {
                const float4* xp = (const float4*)(X + (size_t)n * 128 + s * 32 + g * 8);
                float4 x0 = xp[0], x1 = xp[1];
                fa.u[0] = ((unsigned)f2bf(x0.y) << 16) | f2bf(x0.x);
                fa.u[1] = ((unsigned)f2bf(x0.w) << 16) | f2bf(x0.z);
                fa.u[2] = ((unsigned)f2bf(x1.y) << 16) | f2bf(x1.x);
                fa.u[3] = ((unsigned)f2bf(x1.w) << 16) | f2bf(x1.z);
            } else {
                fa.u[0] = fa.u[1] = fa.u[2] = fa.u[3] = 0u;
            }
            a[h] = fa.s8;
        }
        #pragma unroll
        for (int c = 0; c < 8; ++c) {
            int wr = 16 * c + r;
            short8v b = *(const short8v*)(ldsb + wr * 256 + (((s * 4 + g) ^ (wr & 15)) << 4));
            acc[0][c] = MFMA16(a[0], b, acc[0][c]);
            acc[1][c] = MFMA16(a[1], b, acc[1][c]);
        }
    }
    __syncthreads();

    // bias + tanh + stage bf16 tile
    #pragma unroll
    for (int h = 0; h < 2; ++h) {
        #pragma unroll
        for (int c = 0; c < 8; ++c) {
            #pragma unroll
            for (int q = 0; q < 4; ++q) {
                int rr = w * 32 + h * 16 + g * 4 + q;
                int cb = (16 * c + r) * 2;
                *(unsigned short*)(ldsb + rr * 256 + (((cb >> 4) ^ (rr & 15)) << 4) + (cb & 15)) =
                    f2bf(fast_tanh(acc[h][c][q] + bcol[c]));
            }
        }
    }
    __syncthreads();

    {   // coalesced stores, scattered rows via order
        int rr = tid >> 1, half = tid & 1;
        int n = order[i0 + rr];
        if (n >= 0) {
            uint4* dst = (uint4*)(A0 + (size_t)n * 128 + half * 64);
            #pragma unroll
            for (int j = 0; j < 8; ++j) {
                int gr = half * 8 + j;
                dst[j] = *(const uint4*)(ldsb + rr * 256 + ((gr ^ (rr & 15)) << 4));
            }
        }
    }
}

// ---------------- aggregation (bf16 in) ----------------

__global__ __launch_bounds__(NT) void k_agg_bb(const unsigned short* __restrict__ Y,
                                               const int* __restrict__ rowptr,
                                               const int* __restrict__ col,
                                               const float* __restrict__ dinv,
                                               const float* __restrict__ bias,
                                               unsigned short* __restrict__ out, int N) {
    int gw = (int)((blockIdx.x * (unsigned)blockDim.x + threadIdx.x) >> 6);
    int lane = threadIdx.x & 63;
    if (gw >= N) return;
    const unsigned int* Yw = (const unsigned int*)Y;
    unsigned int u = Yw[(size_t)gw * 64 + lane];
    float ax = bf_lo(u), ay = bf_hi(u);
    int beg = rowptr[gw], end = rowptr[gw + 1];
    for (int e = beg; e < end; ++e) {
        unsigned int v = Yw[(size_t)col[e] * 64 + lane];
        ax += bf_lo(v);
        ay += bf_hi(v);
    }
    float dn = dinv[gw];
    float2 bb = ((const float2*)bias)[lane];
    float rx = ax * dn + bb.x, ry = ay * dn + bb.y;
    ((unsigned int*)out)[(size_t)gw * 64 + lane] = ((unsigned)f2bf(ry) << 16) | f2bf(rx);
}

__global__ __launch_bounds__(NT) void k_agg_bf(const unsigned short* __restrict__ Y,
                                               const int* __restrict__ rowptr,
                                               const int* __restrict__ col,
                                               const float* __restrict__ dinv,
                                               const float* __restrict__ bias,
                                               float* __restrict__ out, int N) {
    int gw = (int)((blockIdx.x * (unsigned)blockDim.x + threadIdx.x) >> 6);
    int lane = threadIdx.x & 63;
    if (gw >= N) return;
    const unsigned int* Yw = (const unsigned int*)Y;
    unsigned int u = Yw[(size_t)gw * 64 + lane];
    float ax = bf_lo(u), ay = bf_hi(u);
    int beg = rowptr[gw], end = rowptr[gw + 1];
    for (int e = beg; e < end; ++e) {
        unsigned int v = Yw[(size_t)col[e] * 64 + lane];
        ax += bf_lo(v);
        ay += bf_hi(v);
    }
    float dn = dinv[gw];
    float2 bb = ((const float2*)bias)[lane];
    float2 rv;
    rv.x = ax * dn + bb.x;
    rv.y = ay * dn + bb.y;
    ((float2*)out)[(size_t)gw * 64 + lane] = rv;
}

// ---------------- launch ----------------

extern "C" void kernel_launch(void* const* d_in, const int* in_sizes, int n_in,
                              void* d_out, int out_size, void* d_ws, size_t ws_size,
                              hipStream_t stream) {
    const float* X = (const float*)d_in[0];
    const int* ntype = (const int*)d_in[1];
    const int* eidx = (const int*)d_in[3];
    const float* AW = (const float*)d_in[5];
    const float* Ab = (const float*)d_in[6];
    const float* W1 = (const float*)d_in[7];
    const float* b1 = (const float*)d_in[8];
    const float* W2 = (const float*)d_in[9];
    const float* b2 = (const float*)d_in[10];

    int N = in_sizes[0] / HID;
    int E = in_sizes[3] / 2;
    const int* esrc = eidx;
    const int* edst = eidx + E;
    float* out = (float*)d_out;

    int gN = (N + NT - 1) / NT;      // 391  (also = nb2, must be <= 512)
    int gE = (E + NT - 1) / NT;
    int gA = gN + 4;                 // padded bucket blocks (256-aligned starts)
    int Nord = gA * NT;
    int nb = (N + 1023) / 1024;      // <= 512

    char* ws = (char*)d_ws;
    size_t off = 0;
    auto carve = [&](size_t bytes) -> void* {
        void* p = ws + off;
        off += (bytes + 255) & ~(size_t)255;
        return p;
    };
    unsigned short* A0 = (unsigned short*)carve((size_t)N * HID * 2);   // bf16 acts
    unsigned short* Yb = (unsigned short*)carve((size_t)N * HID * 2);   // bf16 mm out
    unsigned short* AWt = (unsigned short*)carve(4 * 16384 * 2);
    unsigned short* W1t = (unsigned short*)carve(16384 * 2);
    unsigned short* W2t = (unsigned short*)carve(16384 * 2);
    int* cnt = (int*)carve((size_t)N * sizeof(int));
    int* rowptr = (int*)carve((size_t)(N + 1) * sizeof(int));
    int* cursor = (int*)carve((size_t)N * sizeof(int));
    float* dinv = (float*)carve((size_t)N * sizeof(float));
    int* order = (int*)carve((size_t)Nord * sizeof(int));
    int* col = (int*)carve((size_t)E * sizeof(int));
    int* blkT = (int*)carve((size_t)4 * gN * sizeof(int));
    int* blkBase = (int*)carve((size_t)4 * gN * sizeof(int));
    int* partials = (int*)carve((size_t)nb * sizeof(int));
    (void)ws_size;
    (void)n_in;
    (void)out_size;

    k_zero<<<gA, NT, 0, stream>>>(cnt, order, N);
    k_hist_edge<<<gE, NT, 0, stream>>>(edst, cnt, E);
    k_hist_type<<<gN, NT, 0, stream>>>(ntype, blkT, gN, N);
    k_prep<<<384, NT, 0, stream>>>(AW, W1, W2, AWt, W1t, W2t);
    k_scan1<<<nb, NT, 0, stream>>>(cnt, partials, N);
    k_scanmeta<<<1, NT, 0, stream>>>(partials, nb, blkT, blkBase, gN, rowptr, N);
    k_scan3<<<nb, NT, 0, stream>>>(cnt, partials, rowptr, cursor, dinv, N);
    k_scatter<<<gN, NT, 0, stream>>>(ntype, blkBase, gN, order, N);
    k_fill<<<gE, NT, 0, stream>>>(esrc, edst, cursor, col, E);

    int bMM = (N + 127) / 128;
    int bAD = 2 * gA;                // Nord / 128

    k_adapt<<<bAD, NT, 0, stream>>>(X, ntype, order, AWt, Ab, A0);
    // layer 1
    k_mm<<<bMM, NT, 0, stream>>>(A0, W1t, dinv, Yb, N);
    k_agg_bb<<<(N + 3) / 4, NT, 0, stream>>>(Yb, rowptr, col, dinv, b1, A0, N);
    // layer 2
    k_mm<<<bMM, NT, 0, stream>>>(A0, W2t, dinv, Yb, N);
    k_agg_bf<<<(N + 3) / 4, NT, 0, stream>>>(Yb, rowptr, col, dinv, b2, out, N);
}

// Round 5
// 237.330 us; speedup vs baseline: 3.5690x; 1.2835x over previous
//
#include <hip/hip_runtime.h>
#include <hip/hip_bf16.h>
#include <cmath>

#define NT 256
#define HID 128

typedef __attribute__((ext_vector_type(8))) short short8v;   // 8 bf16 = 4 VGPR
typedef __attribute__((ext_vector_type(4))) float f32x4;

__device__ __forceinline__ unsigned short f2bf(float f) {
    __hip_bfloat16 h(f);
    return __builtin_bit_cast(unsigned short, h);
}
__device__ __forceinline__ float bf_lo(unsigned int u) { return __uint_as_float(u << 16); }
__device__ __forceinline__ float bf_hi(unsigned int u) { return __uint_as_float(u & 0xffff0000u); }

__device__ __forceinline__ float fast_tanh(float x) {
    float cx = fminf(fmaxf(x, -15.f), 15.f);
    float e = __expf(2.f * cx);
    return (e - 1.f) / (e + 1.f);
}

#define MFMA16(a, b, c) __builtin_amdgcn_mfma_f32_16x16x32_bf16(a, b, c, 0, 0, 0)

// ---------------- setup kernels ----------------

__global__ void k_zero(int* __restrict__ cnt, int* __restrict__ order, int N) {
    int i = blockIdx.x * blockDim.x + threadIdx.x;
    order[i] = -1;
    if (i < N) cnt[i] = 0;
}

__global__ void k_hist_edge(const int* __restrict__ dst, int* __restrict__ cnt, int E) {
    int e = blockIdx.x * blockDim.x + threadIdx.x;
    if (e < E) atomicAdd(&cnt[dst[e]], 1);
}

// per-block type histogram -> blkT[t][b]  (no global atomics)
__global__ void k_hist_type(const int* __restrict__ type, int* __restrict__ blkT,
                            int nb2, int N) {
    __shared__ int h[4];
    int tid = threadIdx.x;
    if (tid < 4) h[tid] = 0;
    __syncthreads();
    int i = blockIdx.x * NT + tid;
    int t = (i < N) ? type[i] : -1;
    int lane = tid & 63;
    #pragma unroll
    for (int tt = 0; tt < 4; ++tt) {
        unsigned long long m = __ballot(t == tt);
        if (lane == 0 && m) atomicAdd(&h[tt], __popcll(m));   // LDS atomic only
    }
    __syncthreads();
    if (tid < 4) blkT[tid * nb2 + blockIdx.x] = h[tid];
}

// block-sum of 1024 cnt entries -> partials[block]
__global__ void k_scan1(const int* __restrict__ cnt, int* __restrict__ partials, int N) {
    __shared__ int sdata[NT];
    int base = blockIdx.x * 1024;
    int tid = threadIdx.x;
    int s = 0;
    #pragma unroll
    for (int k = 0; k < 4; ++k) {
        int idx = base + tid * 4 + k;
        if (idx < N) s += cnt[idx];
    }
    sdata[tid] = s;
    __syncthreads();
    for (int off = NT / 2; off > 0; off >>= 1) {
        if (tid < off) sdata[tid] += sdata[tid + off];
        __syncthreads();
    }
    if (tid == 0) partials[blockIdx.x] = sdata[0];
}

// one block: parallel scan of partials (nb<=512) AND per-type scans of blkT (nb2<=512)
__global__ void k_scanmeta(int* __restrict__ partials, int nb,
                           const int* __restrict__ blkT, int* __restrict__ blkBase,
                           int nb2, int* __restrict__ rowptr, int N) {
    __shared__ int s[NT];
    __shared__ int carry;
    int tid = threadIdx.x;

    // ---- scan partials (2 elems/thread) ----
    int v0 = (tid * 2 < nb) ? partials[tid * 2] : 0;
    int v1 = (tid * 2 + 1 < nb) ? partials[tid * 2 + 1] : 0;
    int ts = v0 + v1;
    s[tid] = ts;
    __syncthreads();
    for (int off = 1; off < NT; off <<= 1) {
        int x = (tid >= off) ? s[tid - off] : 0;
        __syncthreads();
        s[tid] += x;
        __syncthreads();
    }
    int excl = s[tid] - ts;
    if (tid * 2 < nb) partials[tid * 2] = excl;
    if (tid * 2 + 1 < nb) partials[tid * 2 + 1] = excl + v0;
    if (tid == NT - 1) rowptr[N] = s[NT - 1];
    __syncthreads();

    // ---- per-type block-base scans, buckets 256-aligned ----
    if (tid == 0) carry = 0;
    __syncthreads();
    for (int t = 0; t < 4; ++t) {
        int w0 = (tid * 2 < nb2) ? blkT[t * nb2 + tid * 2] : 0;
        int w1 = (tid * 2 + 1 < nb2) ? blkT[t * nb2 + tid * 2 + 1] : 0;
        int tw = w0 + w1;
        s[tid] = tw;
        __syncthreads();
        for (int off = 1; off < NT; off <<= 1) {
            int x = (tid >= off) ? s[tid - off] : 0;
            __syncthreads();
            s[tid] += x;
            __syncthreads();
        }
        int ex = s[tid] - tw;
        int base = carry;
        if (tid * 2 < nb2) blkBase[t * nb2 + tid * 2] = base + ex;
        if (tid * 2 + 1 < nb2) blkBase[t * nb2 + tid * 2 + 1] = base + ex + w0;
        __syncthreads();
        if (tid == NT - 1) carry = (base + s[NT - 1] + 255) & ~255;
        __syncthreads();
    }
}

// block-local exclusive scan + add partial prefix -> rowptr/cursor/dinv
__global__ void k_scan3(const int* __restrict__ cnt, const int* __restrict__ partials,
                        int* __restrict__ rowptr, int* __restrict__ cursor,
                        float* __restrict__ dinv, int N) {
    __shared__ int sdata[NT];
    int base = blockIdx.x * 1024;
    int tid = threadIdx.x;
    int a[4];
    int s = 0;
    #pragma unroll
    for (int k = 0; k < 4; ++k) {
        int idx = base + tid * 4 + k;
        a[k] = (idx < N) ? cnt[idx] : 0;
        s += a[k];
    }
    sdata[tid] = s;
    __syncthreads();
    for (int off = 1; off < NT; off <<= 1) {
        int v = (tid >= off) ? sdata[tid - off] : 0;
        __syncthreads();
        sdata[tid] += v;
        __syncthreads();
    }
    int excl = sdata[tid] - s;
    int run = partials[blockIdx.x] + excl;
    #pragma unroll
    for (int k = 0; k < 4; ++k) {
        int idx = base + tid * 4 + k;
        if (idx < N) {
            rowptr[idx] = run;
            cursor[idx] = run;
            dinv[idx] = rsqrtf((float)(a[k] + 1));
            run += a[k];
        }
    }
}

// deterministic, atomic-free type-bucketing scatter
__global__ void k_scatter(const int* __restrict__ type, const int* __restrict__ blkBase,
                          int nb2, int* __restrict__ order, int N) {
    __shared__ int wcnt[4][4];   // [wave][type]
    int tid = threadIdx.x, lane = tid & 63, w = tid >> 6;
    int i = blockIdx.x * NT + tid;
    int t = (i < N) ? type[i] : -1;
    unsigned long long below = (1ull << lane) - 1ull;
    unsigned long long mym = 0;
    #pragma unroll
    for (int tt = 0; tt < 4; ++tt) {
        unsigned long long m = __ballot(t == tt);
        if (lane == 0) wcnt[w][tt] = __popcll(m);
        if (t == tt) mym = m;
    }
    __syncthreads();
    if (t >= 0) {
        int off = 0;
        #pragma unroll
        for (int w2 = 0; w2 < 4; ++w2)
            if (w2 < w) off += wcnt[w2][t];
        int pos = blkBase[t * nb2 + blockIdx.x] + off + __popcll(mym & below);
        order[pos] = i;
    }
}

__global__ void k_fill(const int* __restrict__ src, const int* __restrict__ dst,
                       int* __restrict__ cursor, int* __restrict__ col, int E) {
    int e = blockIdx.x * blockDim.x + threadIdx.x;
    if (e < E) {
        int p = atomicAdd(&cursor[dst[e]], 1);
        col[p] = src[e];
    }
}

// convert + transpose weights to bf16: Wt[col][k] = W[k][col]
__global__ void k_prep(const float* __restrict__ AW, const float* __restrict__ W1,
                       const float* __restrict__ W2, unsigned short* __restrict__ AWt,
                       unsigned short* __restrict__ W1t, unsigned short* __restrict__ W2t) {
    int i = blockIdx.x * NT + threadIdx.x;
    if (i < 65536) {
        int t = i >> 14, rem = i & 16383, c = rem >> 7, k = rem & 127;
        AWt[i] = f2bf(AW[t * 16384 + k * 128 + c]);
    } else if (i < 81920) {
        int j = i - 65536, c = j >> 7, k = j & 127;
        W1t[j] = f2bf(W1[k * 128 + c]);
    } else if (i < 98304) {
        int j = i - 81920, c = j >> 7, k = j & 127;
        W2t[j] = f2bf(W2[k * 128 + c]);
    }
}

// ---------------- MFMA matmul kernels ----------------
// Block: 128 rows x 128 cols. 4 waves, each 32 rows (2 rowgroups of 16).
// LDS: Wt staged swizzled (granule-slot ^= row&15), reused for store-transpose.
// mfma_f32_16x16x32_bf16 layouts (m89-verified family):
//   A: lane holds A[lane&15][8*(lane>>4)+j]   B: lane holds B[8*(lane>>4)+j][lane&15]
//   D: col=lane&15, row=4*(lane>>4)+reg

// Y[n] = bf16( (A[n] @ W) * dinv[n] )
__global__ __launch_bounds__(NT) void k_mm(const unsigned short* __restrict__ Ain,
                                           const unsigned short* __restrict__ Wt,
                                           const float* __restrict__ dinv,
                                           unsigned short* __restrict__ Yout, int N) {
    __shared__ unsigned short lds[16384];   // 32 KB
    char* ldsb = (char*)lds;
    const int tid = threadIdx.x;
    const int lane = tid & 63;
    const int w = tid >> 6;
    const int r = lane & 15, g = lane >> 4;

    {   // stage Wt -> LDS (swizzled)
        int row = tid >> 1, half = tid & 1;
        const uint4* src = (const uint4*)(Wt + row * 128 + half * 64);
        #pragma unroll
        for (int j = 0; j < 8; ++j) {
            int gr = half * 8 + j;
            *(uint4*)(ldsb + row * 256 + ((gr ^ (row & 15)) << 4)) = src[j];
        }
    }
    __syncthreads();

    const int rowbase = blockIdx.x * 128 + w * 32;
    f32x4 acc[2][8];
    #pragma unroll
    for (int h = 0; h < 2; ++h)
        #pragma unroll
        for (int c = 0; c < 8; ++c) { acc[h][c][0] = 0.f; acc[h][c][1] = 0.f; acc[h][c][2] = 0.f; acc[h][c][3] = 0.f; }

    #pragma unroll
    for (int s = 0; s < 4; ++s) {
        short8v a[2];
        #pragma unroll
        for (int h = 0; h < 2; ++h) {
            int n = rowbase + h * 16 + r;
            if (n >= N) n = N - 1;   // slop-safe clamp; stores are guarded
            a[h] = *(const short8v*)(Ain + (size_t)n * 128 + s * 32 + g * 8);
        }
        #pragma unroll
        for (int c = 0; c < 8; ++c) {
            int wr = 16 * c + r;
            short8v b = *(const short8v*)(ldsb + wr * 256 + (((s * 4 + g) ^ (wr & 15)) << 4));
            acc[0][c] = MFMA16(a[0], b, acc[0][c]);
            acc[1][c] = MFMA16(a[1], b, acc[1][c]);
        }
    }
    __syncthreads();   // all waves done reading W from LDS

    // scale + stage bf16 tile in LDS (same swizzle)
    #pragma unroll
    for (int h = 0; h < 2; ++h) {
        float dv[4];
        #pragma unroll
        for (int q = 0; q < 4; ++q) {
            int n = rowbase + h * 16 + g * 4 + q;
            dv[q] = (n < N) ? dinv[n] : 0.f;
        }
        #pragma unroll
        for (int c = 0; c < 8; ++c) {
            #pragma unroll
            for (int q = 0; q < 4; ++q) {
                int rr = w * 32 + h * 16 + g * 4 + q;
                int cb = (16 * c + r) * 2;
                *(unsigned short*)(ldsb + rr * 256 + (((cb >> 4) ^ (rr & 15)) << 4) + (cb & 15)) =
                    f2bf(acc[h][c][q] * dv[q]);
            }
        }
    }
    __syncthreads();

    {   // coalesced full-line stores
        int rr = tid >> 1, half = tid & 1;
        int n = blockIdx.x * 128 + rr;
        if (n < N) {
            uint4* dst = (uint4*)(Yout + (size_t)n * 128 + half * 64);
            #pragma unroll
            for (int j = 0; j < 8; ++j) {
                int gr = half * 8 + j;
                dst[j] = *(const uint4*)(ldsb + rr * 256 + ((gr ^ (rr & 15)) << 4));
            }
        }
    }
}

// A0[n] = bf16( tanh(X[n] @ AW[type[n]] + Ab[type[n]]) ), via type-bucketed order
__global__ __launch_bounds__(NT) void k_adapt(const float* __restrict__ X,
                                              const int* __restrict__ type,
                                              const int* __restrict__ order,
                                              const unsigned short* __restrict__ AWt,
                                              const float* __restrict__ Ab,
                                              unsigned short* __restrict__ A0) {
    __shared__ unsigned short lds[16384];
    char* ldsb = (char*)lds;
    const int i0 = blockIdx.x * 128;
    int n0 = order[i0];
    if (n0 < 0) return;          // whole block is padding
    const int tid = threadIdx.x;
    const int lane = tid & 63;
    const int w = tid >> 6;
    const int r = lane & 15, g = lane >> 4;
    const int t = __builtin_amdgcn_readfirstlane(type[n0]);
    const unsigned short* Wt = AWt + t * 16384;

    {   // stage Wt -> LDS
        int row = tid >> 1, half = tid & 1;
        const uint4* src = (const uint4*)(Wt + row * 128 + half * 64);
        #pragma unroll
        for (int j = 0; j < 8; ++j) {
            int gr = half * 8 + j;
            *(uint4*)(ldsb + row * 256 + ((gr ^ (row & 15)) << 4)) = src[j];
        }
    }
    __syncthreads();

    int nidx[2];
    nidx[0] = order[i0 + w * 32 + r];
    nidx[1] = order[i0 + w * 32 + 16 + r];
    float bcol[8];
    #pragma unroll
    for (int c = 0; c < 8; ++c) bcol[c] = Ab[t * 128 + 16 * c + r];

    f32x4 acc[2][8];
    #pragma unroll
    for (int h = 0; h < 2; ++h)
        #pragma unroll
        for (int c = 0; c < 8; ++c) { acc[h][c][0] = 0.f; acc[h][c][1] = 0.f; acc[h][c][2] = 0.f; acc[h][c][3] = 0.f; }

    #pragma unroll
    for (int s = 0; s < 4; ++s) {
        short8v a[2];
        #pragma unroll
        for (int h = 0; h < 2; ++h) {
            union { short8v s8; unsigned int u[4]; } fa;
            int n = nidx[h];
            if (n >= 0) {
                const float4* xp = (const float4*)(X + (size_t)n * 128 + s * 32 + g * 8);
                float4 x0 = xp[0], x1 = xp[1];
                fa.u[0] = ((unsigned)f2bf(x0.y) << 16) | f2bf(x0.x);
                fa.u[1] = ((unsigned)f2bf(x0.w) << 16) | f2bf(x0.z);
                fa.u[2] = ((unsigned)f2bf(x1.y) << 16) | f2bf(x1.x);
                fa.u[3] = ((unsigned)f2bf(x1.w) << 16) | f2bf(x1.z);
            } else {
                fa.u[0] = fa.u[1] = fa.u[2] = fa.u[3] = 0u;
            }
            a[h] = fa.s8;
        }
        #pragma unroll
        for (int c = 0; c < 8; ++c) {
            int wr = 16 * c + r;
            short8v b = *(const short8v*)(ldsb + wr * 256 + (((s * 4 + g) ^ (wr & 15)) << 4));
            acc[0][c] = MFMA16(a[0], b, acc[0][c]);
            acc[1][c] = MFMA16(a[1], b, acc[1][c]);
        }
    }
    __syncthreads();

    // bias + tanh + stage bf16 tile
    #pragma unroll
    for (int h = 0; h < 2; ++h) {
        #pragma unroll
        for (int c = 0; c < 8; ++c) {
            #pragma unroll
            for (int q = 0; q < 4; ++q) {
                int rr = w * 32 + h * 16 + g * 4 + q;
                int cb = (16 * c + r) * 2;
                *(unsigned short*)(ldsb + rr * 256 + (((cb >> 4) ^ (rr & 15)) << 4) + (cb & 15)) =
                    f2bf(fast_tanh(acc[h][c][q] + bcol[c]));
            }
        }
    }
    __syncthreads();

    {   // coalesced stores, scattered rows via order
        int rr = tid >> 1, half = tid & 1;
        int n = order[i0 + rr];
        if (n >= 0) {
            uint4* dst = (uint4*)(A0 + (size_t)n * 128 + half * 64);
            #pragma unroll
            for (int j = 0; j < 8; ++j) {
                int gr = half * 8 + j;
                dst[j] = *(const uint4*)(ldsb + rr * 256 + ((gr ^ (rr & 15)) << 4));
            }
        }
    }
}

// ---------------- aggregation (bf16 in, MLP-batched gathers) ----------------
// Per node (1 wave): coalesced load of up to 64 col indices, then 4 independent
// row-gathers in flight per step; tail padded with self-row loads weighted 0.

__device__ __forceinline__ void agg_core(const unsigned int* __restrict__ Yw,
                                         const int* __restrict__ rowptr,
                                         const int* __restrict__ col,
                                         int gw, int lane, float& ax, float& ay) {
    unsigned int u = Yw[(size_t)gw * 64 + lane];
    ax = bf_lo(u);
    ay = bf_hi(u);
    int beg = rowptr[gw], end = rowptr[gw + 1];
    for (int base = beg; base < end; base += 64) {
        int m = end - base;
        if (m > 64) m = 64;
        int ce = (lane < m) ? col[base + lane] : gw;
        for (int k = 0; k < m; k += 4) {
            int s0 = __shfl(ce, k);
            int s1 = __shfl(ce, (k + 1 < m) ? k + 1 : 0);
            int s2 = __shfl(ce, (k + 2 < m) ? k + 2 : 0);
            int s3 = __shfl(ce, (k + 3 < m) ? k + 3 : 0);
            unsigned int v0 = Yw[(size_t)s0 * 64 + lane];
            unsigned int v1 = Yw[(size_t)s1 * 64 + lane];
            unsigned int v2 = Yw[(size_t)s2 * 64 + lane];
            unsigned int v3 = Yw[(size_t)s3 * 64 + lane];
            float w1 = (k + 1 < m) ? 1.f : 0.f;
            float w2 = (k + 2 < m) ? 1.f : 0.f;
            float w3 = (k + 3 < m) ? 1.f : 0.f;
            ax += bf_lo(v0);
            ay += bf_hi(v0);
            ax = fmaf(w1, bf_lo(v1), ax);
            ay = fmaf(w1, bf_hi(v1), ay);
            ax = fmaf(w2, bf_lo(v2), ax);
            ay = fmaf(w2, bf_hi(v2), ay);
            ax = fmaf(w3, bf_lo(v3), ax);
            ay = fmaf(w3, bf_hi(v3), ay);
        }
    }
}

__global__ __launch_bounds__(NT) void k_agg_bb(const unsigned short* __restrict__ Y,
                                               const int* __restrict__ rowptr,
                                               const int* __restrict__ col,
                                               const float* __restrict__ dinv,
                                               const float* __restrict__ bias,
                                               unsigned short* __restrict__ out, int N) {
    int gw = (int)((blockIdx.x * (unsigned)blockDim.x + threadIdx.x) >> 6);
    int lane = threadIdx.x & 63;
    if (gw >= N) return;
    float ax, ay;
    agg_core((const unsigned int*)Y, rowptr, col, gw, lane, ax, ay);
    float dn = dinv[gw];
    float2 bb = ((const float2*)bias)[lane];
    float rx = ax * dn + bb.x, ry = ay * dn + bb.y;
    ((unsigned int*)out)[(size_t)gw * 64 + lane] = ((unsigned)f2bf(ry) << 16) | f2bf(rx);
}

__global__ __launch_bounds__(NT) void k_agg_bf(const unsigned short* __restrict__ Y,
                                               const int* __restrict__ rowptr,
                                               const int* __restrict__ col,
                                               const float* __restrict__ dinv,
                                               const float* __restrict__ bias,
                                               float* __restrict__ out, int N) {
    int gw = (int)((blockIdx.x * (unsigned)blockDim.x + threadIdx.x) >> 6);
    int lane = threadIdx.x & 63;
    if (gw >= N) return;
    float ax, ay;
    agg_core((const unsigned int*)Y, rowptr, col, gw, lane, ax, ay);
    float dn = dinv[gw];
    float2 bb = ((const float2*)bias)[lane];
    float2 rv;
    rv.x = ax * dn + bb.x;
    rv.y = ay * dn + bb.y;
    ((float2*)out)[(size_t)gw * 64 + lane] = rv;
}

// ---------------- launch ----------------

extern "C" void kernel_launch(void* const* d_in, const int* in_sizes, int n_in,
                              void* d_out, int out_size, void* d_ws, size_t ws_size,
                              hipStream_t stream) {
    const float* X = (const float*)d_in[0];
    const int* ntype = (const int*)d_in[1];
    const int* eidx = (const int*)d_in[3];
    const float* AW = (const float*)d_in[5];
    const float* Ab = (const float*)d_in[6];
    const float* W1 = (const float*)d_in[7];
    const float* b1 = (const float*)d_in[8];
    const float* W2 = (const float*)d_in[9];
    const float* b2 = (const float*)d_in[10];

    int N = in_sizes[0] / HID;
    int E = in_sizes[3] / 2;
    const int* esrc = eidx;
    const int* edst = eidx + E;
    float* out = (float*)d_out;

    int gN = (N + NT - 1) / NT;      // 391  (also = nb2, must be <= 512)
    int gE = (E + NT - 1) / NT;
    int gA = gN + 4;                 // padded bucket blocks (256-aligned starts)
    int Nord = gA * NT;
    int nb = (N + 1023) / 1024;      // <= 512

    char* ws = (char*)d_ws;
    size_t off = 0;
    auto carve = [&](size_t bytes) -> void* {
        void* p = ws + off;
        off += (bytes + 255) & ~(size_t)255;
        return p;
    };
    unsigned short* A0 = (unsigned short*)carve((size_t)N * HID * 2);   // bf16 acts
    unsigned short* Yb = (unsigned short*)carve((size_t)N * HID * 2);   // bf16 mm out
    unsigned short* AWt = (unsigned short*)carve(4 * 16384 * 2);
    unsigned short* W1t = (unsigned short*)carve(16384 * 2);
    unsigned short* W2t = (unsigned short*)carve(16384 * 2);
    int* cnt = (int*)carve((size_t)N * sizeof(int));
    int* rowptr = (int*)carve((size_t)(N + 1) * sizeof(int));
    int* cursor = (int*)carve((size_t)N * sizeof(int));
    float* dinv = (float*)carve((size_t)N * sizeof(float));
    int* order = (int*)carve((size_t)Nord * sizeof(int));
    int* col = (int*)carve((size_t)E * sizeof(int));
    int* blkT = (int*)carve((size_t)4 * gN * sizeof(int));
    int* blkBase = (int*)carve((size_t)4 * gN * sizeof(int));
    int* partials = (int*)carve((size_t)nb * sizeof(int));
    (void)ws_size;
    (void)n_in;
    (void)out_size;

    k_zero<<<gA, NT, 0, stream>>>(cnt, order, N);
    k_hist_edge<<<gE, NT, 0, stream>>>(edst, cnt, E);
    k_hist_type<<<gN, NT, 0, stream>>>(ntype, blkT, gN, N);
    k_prep<<<384, NT, 0, stream>>>(AW, W1, W2, AWt, W1t, W2t);
    k_scan1<<<nb, NT, 0, stream>>>(cnt, partials, N);
    k_scanmeta<<<1, NT, 0, stream>>>(partials, nb, blkT, blkBase, gN, rowptr, N);
    k_scan3<<<nb, NT, 0, stream>>>(cnt, partials, rowptr, cursor, dinv, N);
    k_scatter<<<gN, NT, 0, stream>>>(ntype, blkBase, gN, order, N);
    k_fill<<<gE, NT, 0, stream>>>(esrc, edst, cursor, col, E);

    int bMM = (N + 127) / 128;
    int bAD = 2 * gA;                // Nord / 128

    k_adapt<<<bAD, NT, 0, stream>>>(X, ntype, order, AWt, Ab, A0);
    // layer 1
    k_mm<<<bMM, NT, 0, stream>>>(A0, W1t, dinv, Yb, N);
    k_agg_bb<<<(N + 3) / 4, NT, 0, stream>>>(Yb, rowptr, col, dinv, b1, A0, N);
    // layer 2
    k_mm<<<bMM, NT, 0, stream>>>(A0, W2t, dinv, Yb, N);
    k_agg_bf<<<(N + 3) / 4, NT, 0, stream>>>(Yb, rowptr, col, dinv, b2, out, N);
}

// Round 6
// 229.104 us; speedup vs baseline: 3.6971x; 1.0359x over previous
//
#include <hip/hip_runtime.h>
#include <hip/hip_bf16.h>
#include <cmath>

#define NT 256
#define HID 128

typedef __attribute__((ext_vector_type(8))) short short8v;   // 8 bf16 = 4 VGPR
typedef __attribute__((ext_vector_type(4))) float f32x4;

__device__ __forceinline__ unsigned short f2bf(float f) {
    __hip_bfloat16 h(f);
    return __builtin_bit_cast(unsigned short, h);
}
__device__ __forceinline__ float bf_lo(unsigned int u) { return __uint_as_float(u << 16); }
__device__ __forceinline__ float bf_hi(unsigned int u) { return __uint_as_float(u & 0xffff0000u); }

// cheap round-half-up bf16 pack (inputs finite)
__device__ __forceinline__ unsigned pk(float lo, float hi) {
    unsigned ul = __float_as_uint(lo), uh = __float_as_uint(hi);
    return ((ul + 0x8000u) >> 16) | ((uh + 0x8000u) & 0xffff0000u);
}
__device__ __forceinline__ unsigned short bf1(float v) {
    return (unsigned short)((__float_as_uint(v) + 0x8000u) >> 16);
}

__device__ __forceinline__ float fast_tanh(float x) {
    float cx = fminf(fmaxf(x, -15.f), 15.f);
    float e = __expf(2.f * cx);
    return (e - 1.f) / (e + 1.f);
}

#define MFMA16(a, b, c) __builtin_amdgcn_mfma_f32_16x16x32_bf16(a, b, c, 0, 0, 0)

// ---------------- setup kernels ----------------

__global__ void k_zero(int* __restrict__ cnt, int* __restrict__ order, int N) {
    int i = blockIdx.x * blockDim.x + threadIdx.x;
    order[i] = -1;
    if (i < N) cnt[i] = 0;
}

__global__ void k_hist_edge(const int* __restrict__ dst, int* __restrict__ cnt, int E) {
    int e = blockIdx.x * blockDim.x + threadIdx.x;
    if (e < E) atomicAdd(&cnt[dst[e]], 1);
}

// per-block type histogram -> blkT[t][b]  (no global atomics)
__global__ void k_hist_type(const int* __restrict__ type, int* __restrict__ blkT,
                            int nb2, int N) {
    __shared__ int h[4];
    int tid = threadIdx.x;
    if (tid < 4) h[tid] = 0;
    __syncthreads();
    int i = blockIdx.x * NT + tid;
    int t = (i < N) ? type[i] : -1;
    int lane = tid & 63;
    #pragma unroll
    for (int tt = 0; tt < 4; ++tt) {
        unsigned long long m = __ballot(t == tt);
        if (lane == 0 && m) atomicAdd(&h[tt], __popcll(m));   // LDS atomic only
    }
    __syncthreads();
    if (tid < 4) blkT[tid * nb2 + blockIdx.x] = h[tid];
}

// block-sum of 1024 cnt entries -> partials[block]
__global__ void k_scan1(const int* __restrict__ cnt, int* __restrict__ partials, int N) {
    __shared__ int sdata[NT];
    int base = blockIdx.x * 1024;
    int tid = threadIdx.x;
    int s = 0;
    #pragma unroll
    for (int k = 0; k < 4; ++k) {
        int idx = base + tid * 4 + k;
        if (idx < N) s += cnt[idx];
    }
    sdata[tid] = s;
    __syncthreads();
    for (int off = NT / 2; off > 0; off >>= 1) {
        if (tid < off) sdata[tid] += sdata[tid + off];
        __syncthreads();
    }
    if (tid == 0) partials[blockIdx.x] = sdata[0];
}

// one block: parallel scan of partials (nb<=512) AND per-type scans of blkT (nb2<=512)
__global__ void k_scanmeta(int* __restrict__ partials, int nb,
                           const int* __restrict__ blkT, int* __restrict__ blkBase,
                           int nb2, int* __restrict__ rowptr, int N) {
    __shared__ int s[NT];
    __shared__ int carry;
    int tid = threadIdx.x;

    int v0 = (tid * 2 < nb) ? partials[tid * 2] : 0;
    int v1 = (tid * 2 + 1 < nb) ? partials[tid * 2 + 1] : 0;
    int ts = v0 + v1;
    s[tid] = ts;
    __syncthreads();
    for (int off = 1; off < NT; off <<= 1) {
        int x = (tid >= off) ? s[tid - off] : 0;
        __syncthreads();
        s[tid] += x;
        __syncthreads();
    }
    int excl = s[tid] - ts;
    if (tid * 2 < nb) partials[tid * 2] = excl;
    if (tid * 2 + 1 < nb) partials[tid * 2 + 1] = excl + v0;
    if (tid == NT - 1) rowptr[N] = s[NT - 1];
    __syncthreads();

    if (tid == 0) carry = 0;
    __syncthreads();
    for (int t = 0; t < 4; ++t) {
        int w0 = (tid * 2 < nb2) ? blkT[t * nb2 + tid * 2] : 0;
        int w1 = (tid * 2 + 1 < nb2) ? blkT[t * nb2 + tid * 2 + 1] : 0;
        int tw = w0 + w1;
        s[tid] = tw;
        __syncthreads();
        for (int off = 1; off < NT; off <<= 1) {
            int x = (tid >= off) ? s[tid - off] : 0;
            __syncthreads();
            s[tid] += x;
            __syncthreads();
        }
        int ex = s[tid] - tw;
        int base = carry;
        if (tid * 2 < nb2) blkBase[t * nb2 + tid * 2] = base + ex;
        if (tid * 2 + 1 < nb2) blkBase[t * nb2 + tid * 2 + 1] = base + ex + w0;
        __syncthreads();
        if (tid == NT - 1) carry = (base + s[NT - 1] + 255) & ~255;
        __syncthreads();
    }
}

// block-local exclusive scan + add partial prefix -> rowptr/cursor/dinv
__global__ void k_scan3(const int* __restrict__ cnt, const int* __restrict__ partials,
                        int* __restrict__ rowptr, int* __restrict__ cursor,
                        float* __restrict__ dinv, int N) {
    __shared__ int sdata[NT];
    int base = blockIdx.x * 1024;
    int tid = threadIdx.x;
    int a[4];
    int s = 0;
    #pragma unroll
    for (int k = 0; k < 4; ++k) {
        int idx = base + tid * 4 + k;
        a[k] = (idx < N) ? cnt[idx] : 0;
        s += a[k];
    }
    sdata[tid] = s;
    __syncthreads();
    for (int off = 1; off < NT; off <<= 1) {
        int v = (tid >= off) ? sdata[tid - off] : 0;
        __syncthreads();
        sdata[tid] += v;
        __syncthreads();
    }
    int excl = sdata[tid] - s;
    int run = partials[blockIdx.x] + excl;
    #pragma unroll
    for (int k = 0; k < 4; ++k) {
        int idx = base + tid * 4 + k;
        if (idx < N) {
            rowptr[idx] = run;
            cursor[idx] = run;
            dinv[idx] = rsqrtf((float)(a[k] + 1));
            run += a[k];
        }
    }
}

// deterministic, atomic-free type-bucketing scatter
__global__ void k_scatter(const int* __restrict__ type, const int* __restrict__ blkBase,
                          int nb2, int* __restrict__ order, int N) {
    __shared__ int wcnt[4][4];   // [wave][type]
    int tid = threadIdx.x, lane = tid & 63, w = tid >> 6;
    int i = blockIdx.x * NT + tid;
    int t = (i < N) ? type[i] : -1;
    unsigned long long below = (1ull << lane) - 1ull;
    unsigned long long mym = 0;
    #pragma unroll
    for (int tt = 0; tt < 4; ++tt) {
        unsigned long long m = __ballot(t == tt);
        if (lane == 0) wcnt[w][tt] = __popcll(m);
        if (t == tt) mym = m;
    }
    __syncthreads();
    if (t >= 0) {
        int off = 0;
        #pragma unroll
        for (int w2 = 0; w2 < 4; ++w2)
            if (w2 < w) off += wcnt[w2][t];
        int pos = blkBase[t * nb2 + blockIdx.x] + off + __popcll(mym & below);
        order[pos] = i;
    }
}

__global__ void k_fill(const int* __restrict__ src, const int* __restrict__ dst,
                       int* __restrict__ cursor, int* __restrict__ col, int E) {
    int e = blockIdx.x * blockDim.x + threadIdx.x;
    if (e < E) {
        int p = atomicAdd(&cursor[dst[e]], 1);
        col[p] = src[e];
    }
}

// convert + transpose weights to bf16: Wt[col][k] = W[k][col]
__global__ void k_prep(const float* __restrict__ AW, const float* __restrict__ W1,
                       const float* __restrict__ W2, unsigned short* __restrict__ AWt,
                       unsigned short* __restrict__ W1t, unsigned short* __restrict__ W2t) {
    int i = blockIdx.x * NT + threadIdx.x;
    if (i < 65536) {
        int t = i >> 14, rem = i & 16383, c = rem >> 7, k = rem & 127;
        AWt[i] = f2bf(AW[t * 16384 + k * 128 + c]);
    } else if (i < 81920) {
        int j = i - 65536, c = j >> 7, k = j & 127;
        W1t[j] = f2bf(W1[k * 128 + c]);
    } else if (i < 98304) {
        int j = i - 81920, c = j >> 7, k = j & 127;
        W2t[j] = f2bf(W2[k * 128 + c]);
    }
}

// ---------------- main kernels ----------------
// 64-row blocks, 4 waves x 16 rows. LDS: buf0 = W (32KB, swizzled), buf1 = row tile (16KB).
// mfma_f32_16x16x32_bf16 (m89 layouts): A lane: A[lane&15][8*(lane>>4)+j];
// B lane: B[8*(lane>>4)+j][lane&15]; D: col=lane&15, row=4*(lane>>4)+reg.

// A0d[n] = bf16( tanh(X[n]@AW[t] + Ab[t]) * dinv[n] ), nodes via type-bucketed order
__global__ __launch_bounds__(NT) void k_adapt(const float* __restrict__ X,
                                              const int* __restrict__ type,
                                              const int* __restrict__ order,
                                              const unsigned short* __restrict__ AWt,
                                              const float* __restrict__ Ab,
                                              const float* __restrict__ dinv,
                                              unsigned short* __restrict__ A0d) {
    __shared__ unsigned short lds[24576];   // 48 KB
    char* ldsb = (char*)lds;                // buf0: W
    char* Tb = ldsb + 32768;                // buf1: tile
    const int i0 = blockIdx.x * 64;
    int n0 = order[i0];
    if (n0 < 0) return;                     // all-padding block
    const int tid = threadIdx.x;
    const int lane = tid & 63;
    const int w = tid >> 6;
    const int r = lane & 15, g = lane >> 4;
    const int t = __builtin_amdgcn_readfirstlane(type[n0]);
    const unsigned short* Wt = AWt + t * 16384;

    {   // stage W -> LDS (swizzled)
        int row = tid >> 1, half = tid & 1;
        const uint4* src = (const uint4*)(Wt + row * 128 + half * 64);
        #pragma unroll
        for (int j = 0; j < 8; ++j) {
            int gr = half * 8 + j;
            *(uint4*)(ldsb + row * 256 + ((gr ^ (row & 15)) << 4)) = src[j];
        }
    }

    int oid = order[i0 + w * 16 + r];
    float dvl = (oid >= 0) ? dinv[oid] : 0.f;

    float4 xv[8];
    if (oid >= 0) {
        const float4* xp = (const float4*)(X + (size_t)oid * 128);
        #pragma unroll
        for (int s = 0; s < 4; ++s) {
            xv[2 * s] = xp[s * 8 + g * 2];
            xv[2 * s + 1] = xp[s * 8 + g * 2 + 1];
        }
    } else {
        #pragma unroll
        for (int k = 0; k < 8; ++k) xv[k] = float4{0.f, 0.f, 0.f, 0.f};
    }

    float bcol[8];
    #pragma unroll
    for (int c = 0; c < 8; ++c) bcol[c] = Ab[t * 128 + c * 16 + r];

    f32x4 acc[8];
    #pragma unroll
    for (int c = 0; c < 8; ++c) { acc[c][0] = 0.f; acc[c][1] = 0.f; acc[c][2] = 0.f; acc[c][3] = 0.f; }

    __syncthreads();   // W ready

    #pragma unroll
    for (int s = 0; s < 4; ++s) {
        union { short8v s8; unsigned u[4]; } a;
        a.u[0] = pk(xv[2 * s].x, xv[2 * s].y);
        a.u[1] = pk(xv[2 * s].z, xv[2 * s].w);
        a.u[2] = pk(xv[2 * s + 1].x, xv[2 * s + 1].y);
        a.u[3] = pk(xv[2 * s + 1].z, xv[2 * s + 1].w);
        int slot = s * 4 + g;
        #pragma unroll
        for (int c = 0; c < 8; ++c) {
            int wr = 16 * c + r;
            short8v b = *(const short8v*)(ldsb + wr * 256 + ((slot ^ (wr & 15)) << 4));
            acc[c] = MFMA16(a.s8, b, acc[c]);
        }
    }

    float dn[4];
    #pragma unroll
    for (int q = 0; q < 4; ++q) dn[q] = __shfl(dvl, 4 * g + q);
    #pragma unroll
    for (int c = 0; c < 8; ++c) {
        #pragma unroll
        for (int q = 0; q < 4; ++q) {
            int row = w * 16 + 4 * g + q;
            int cb = (c * 16 + r) * 2;
            float v = fast_tanh(acc[c][q] + bcol[c]) * dn[q];
            *(unsigned short*)(Tb + row * 256 + (((cb >> 4) ^ (row & 15)) << 4) + (cb & 15)) = bf1(v);
        }
    }
    // stores: wave-local rows (wave w wrote rows w*16..w*16+15; tid>>2 maps the same way)
    int row = tid >> 2;
    int d = order[i0 + row];
    if (d >= 0) {
        unsigned short* dst = A0d + (size_t)d * 128;
        #pragma unroll
        for (int k = 0; k < 4; ++k) {
            int gr = (tid & 3) * 4 + k;
            uint4 v = *(const uint4*)(Tb + row * 256 + ((gr ^ (row & 15)) << 4));
            *(uint4*)(dst + gr * 8) = v;
        }
    }
}

// Fused gather-sum + GEMM.  S[d] = dinv[d]*(Yin[d] + sum_{src} Yin[src]);
// OUTF32=false: out_bf16[d] = (S@W + bias)*dinv[d];  OUTF32=true: out_f32[d] = S@W + bias.
template <bool OUTF32>
__global__ __launch_bounds__(NT) void k_layer(const unsigned short* __restrict__ Yin,
                                              const int* __restrict__ rowptr,
                                              const int* __restrict__ col,
                                              const float* __restrict__ dinv,
                                              const unsigned short* __restrict__ Wt,
                                              const float* __restrict__ bias,
                                              void* __restrict__ outp, int N) {
    __shared__ unsigned short lds[24576];   // 48 KB
    char* ldsb = (char*)lds;                // buf0: W (reused as f32 tile when OUTF32)
    char* Tb = ldsb + 32768;                // buf1: S tile
    const int tid = threadIdx.x;
    const int lane = tid & 63;
    const int w = tid >> 6;
    const int r = lane & 15, g = lane >> 4;

    {   // stage W -> LDS (swizzled)
        int row = tid >> 1, half = tid & 1;
        const uint4* src = (const uint4*)(Wt + row * 128 + half * 64);
        #pragma unroll
        for (int j = 0; j < 8; ++j) {
            int gr = half * 8 + j;
            *(uint4*)(ldsb + row * 256 + ((gr ^ (row & 15)) << 4)) = src[j];
        }
    }

    const int nbase = blockIdx.x * 64 + w * 16;
    const unsigned int* Yw = (const unsigned int*)Yin;

    int rp = 0;
    if (lane < 17) { int idx = nbase + lane; rp = rowptr[(idx < N) ? idx : N]; }
    float dvl = 0.f;
    if (lane < 16) { int idx = nbase + lane; if (idx < N) dvl = dinv[idx]; }

    // ---- gather phase: 2 groups of 8 nodes, 16 gathers in flight ----
    #pragma unroll
    for (int q8 = 0; q8 < 2; ++q8) {
        float ax[8], ay[8];
        int beg[8], len[8], pad[8];
        int ml = 0;
        #pragma unroll
        for (int j = 0; j < 8; ++j) {
            int d = nbase + q8 * 8 + j;
            int b = __shfl(rp, q8 * 8 + j);
            int e = __shfl(rp, q8 * 8 + j + 1);
            bool valid = d < N;
            beg[j] = b;
            len[j] = valid ? (e - b) : 0;
            pad[j] = valid ? d : 0;
            unsigned u = valid ? Yw[(size_t)d * 64 + lane] : 0u;   // self term
            ax[j] = bf_lo(u);
            ay[j] = bf_hi(u);
            ml = max(ml, len[j]);
        }
        for (int base = 0; base < ml; base += 64) {
            int ce[8];
            #pragma unroll
            for (int j = 0; j < 8; ++j) {
                int rem = len[j] - base;
                ce[j] = (lane < rem) ? col[beg[j] + base + lane] : pad[j];
            }
            int rounds = ml - base;
            if (rounds > 64) rounds = 64;
            for (int rr = 0; rr < rounds; rr += 2) {
                int rr1 = (rr + 1 < rounds) ? rr + 1 : rr;
                unsigned v0[8], v1[8];
                #pragma unroll
                for (int j = 0; j < 8; ++j) {
                    int sa = __shfl(ce[j], rr);
                    int sb = __shfl(ce[j], rr1);
                    v0[j] = Yw[(size_t)sa * 64 + lane];
                    v1[j] = Yw[(size_t)sb * 64 + lane];
                }
                #pragma unroll
                for (int j = 0; j < 8; ++j) {
                    float w0 = (base + rr < len[j]) ? 1.f : 0.f;
                    float w1 = (rr + 1 < rounds && base + rr + 1 < len[j]) ? 1.f : 0.f;
                    ax[j] = fmaf(w0, bf_lo(v0[j]), ax[j]);
                    ay[j] = fmaf(w0, bf_hi(v0[j]), ay[j]);
                    ax[j] = fmaf(w1, bf_lo(v1[j]), ax[j]);
                    ay[j] = fmaf(w1, bf_hi(v1[j]), ay[j]);
                }
            }
        }
        // write S rows (wave-local region of tile)
        #pragma unroll
        for (int j = 0; j < 8; ++j) {
            int d = nbase + q8 * 8 + j;
            int row = w * 16 + q8 * 8 + j;
            float dn = __shfl(dvl, q8 * 8 + j);
            if (d < N) {
                unsigned p = pk(ax[j] * dn, ay[j] * dn);
                *(unsigned*)(Tb + row * 256 + (((lane >> 2) ^ (row & 15)) << 4) + (lane & 3) * 4) = p;
            }
        }
    }

    __syncthreads();   // W staged; S tile reads below are wave-local

    float bcol[8];
    #pragma unroll
    for (int c = 0; c < 8; ++c) bcol[c] = bias[c * 16 + r];

    f32x4 acc[8];
    #pragma unroll
    for (int c = 0; c < 8; ++c) { acc[c][0] = 0.f; acc[c][1] = 0.f; acc[c][2] = 0.f; acc[c][3] = 0.f; }

    const int arow = w * 16 + r;   // arow & 15 == r
    #pragma unroll
    for (int s = 0; s < 4; ++s) {
        int slot = s * 4 + g;
        short8v a = *(const short8v*)(Tb + arow * 256 + ((slot ^ r) << 4));
        #pragma unroll
        for (int c = 0; c < 8; ++c) {
            int wr = 16 * c + r;
            short8v b = *(const short8v*)(ldsb + wr * 256 + ((slot ^ (wr & 15)) << 4));
            acc[c] = MFMA16(a, b, acc[c]);
        }
    }

    if (OUTF32) {
        __syncthreads();   // all B-reads done before overwriting buf0 with f32 tile
        #pragma unroll
        for (int c = 0; c < 8; ++c) {
            #pragma unroll
            for (int q = 0; q < 4; ++q) {
                int row = w * 16 + 4 * g + q;
                int gran = c * 4 + (r >> 2);
                *(float*)(ldsb + row * 512 + ((gran ^ (row & 7)) << 4) + (r & 3) * 4) =
                    acc[c][q] + bcol[c];
            }
        }
        int row = tid >> 2;           // wave-local rows
        int d = blockIdx.x * 64 + row;
        if (d < N) {
            float* dst = (float*)outp + (size_t)d * 128;
            #pragma unroll
            for (int k = 0; k < 8; ++k) {
                int gran = (tid & 3) * 8 + k;
                uint4 v = *(const uint4*)(ldsb + row * 512 + ((gran ^ (row & 7)) << 4));
                *(uint4*)(dst + gran * 4) = v;
            }
        }
    } else {
        float dn[4];
        #pragma unroll
        for (int q = 0; q < 4; ++q) dn[q] = __shfl(dvl, 4 * g + q);
        #pragma unroll
        for (int c = 0; c < 8; ++c) {
            #pragma unroll
            for (int q = 0; q < 4; ++q) {
                int row = w * 16 + 4 * g + q;
                int cb = (c * 16 + r) * 2;
                float v = (acc[c][q] + bcol[c]) * dn[q];
                *(unsigned short*)(Tb + row * 256 + (((cb >> 4) ^ (row & 15)) << 4) + (cb & 15)) = bf1(v);
            }
        }
        int row = tid >> 2;           // wave-local rows
        int d = blockIdx.x * 64 + row;
        if (d < N) {
            unsigned short* dst = (unsigned short*)outp + (size_t)d * 128;
            #pragma unroll
            for (int k = 0; k < 4; ++k) {
                int gr = (tid & 3) * 4 + k;
                uint4 v = *(const uint4*)(Tb + row * 256 + ((gr ^ (row & 15)) << 4));
                *(uint4*)(dst + gr * 8) = v;
            }
        }
    }
}

// ---------------- launch ----------------

extern "C" void kernel_launch(void* const* d_in, const int* in_sizes, int n_in,
                              void* d_out, int out_size, void* d_ws, size_t ws_size,
                              hipStream_t stream) {
    const float* X = (const float*)d_in[0];
    const int* ntype = (const int*)d_in[1];
    const int* eidx = (const int*)d_in[3];
    const float* AW = (const float*)d_in[5];
    const float* Ab = (const float*)d_in[6];
    const float* W1 = (const float*)d_in[7];
    const float* b1 = (const float*)d_in[8];
    const float* W2 = (const float*)d_in[9];
    const float* b2 = (const float*)d_in[10];

    int N = in_sizes[0] / HID;
    int E = in_sizes[3] / 2;
    const int* esrc = eidx;
    const int* edst = eidx + E;
    float* out = (float*)d_out;

    int gN = (N + NT - 1) / NT;      // also nb2 (<=512)
    int gE = (E + NT - 1) / NT;
    int gA = gN + 4;                 // padded bucket blocks (256-aligned starts)
    int Nord = gA * NT;
    int nb = (N + 1023) / 1024;      // <= 512

    char* ws = (char*)d_ws;
    size_t off = 0;
    auto carve = [&](size_t bytes) -> void* {
        void* p = ws + off;
        off += (bytes + 255) & ~(size_t)255;
        return p;
    };
    unsigned short* A0d = (unsigned short*)carve((size_t)N * HID * 2);  // bf16 adapt out (dinv-scaled)
    unsigned short* H1d = (unsigned short*)carve((size_t)N * HID * 2);  // bf16 layer1 out (dinv-scaled)
    unsigned short* AWt = (unsigned short*)carve(4 * 16384 * 2);
    unsigned short* W1t = (unsigned short*)carve(16384 * 2);
    unsigned short* W2t = (unsigned short*)carve(16384 * 2);
    int* cnt = (int*)carve((size_t)N * sizeof(int));
    int* rowptr = (int*)carve((size_t)(N + 1) * sizeof(int));
    int* cursor = (int*)carve((size_t)N * sizeof(int));
    float* dinv = (float*)carve((size_t)N * sizeof(float));
    int* order = (int*)carve((size_t)Nord * sizeof(int));
    int* col = (int*)carve((size_t)E * sizeof(int));
    int* blkT = (int*)carve((size_t)4 * gN * sizeof(int));
    int* blkBase = (int*)carve((size_t)4 * gN * sizeof(int));
    int* partials = (int*)carve((size_t)nb * sizeof(int));
    (void)ws_size;
    (void)n_in;
    (void)out_size;

    k_zero<<<gA, NT, 0, stream>>>(cnt, order, N);
    k_hist_edge<<<gE, NT, 0, stream>>>(edst, cnt, E);
    k_hist_type<<<gN, NT, 0, stream>>>(ntype, blkT, gN, N);
    k_prep<<<384, NT, 0, stream>>>(AW, W1, W2, AWt, W1t, W2t);
    k_scan1<<<nb, NT, 0, stream>>>(cnt, partials, N);
    k_scanmeta<<<1, NT, 0, stream>>>(partials, nb, blkT, blkBase, gN, rowptr, N);
    k_scan3<<<nb, NT, 0, stream>>>(cnt, partials, rowptr, cursor, dinv, N);
    k_scatter<<<gN, NT, 0, stream>>>(ntype, blkBase, gN, order, N);
    k_fill<<<gE, NT, 0, stream>>>(esrc, edst, cursor, col, E);

    int bA = gA * 4;                 // 64-row blocks over order space
    int bL = (N + 63) / 64;

    k_adapt<<<bA, NT, 0, stream>>>(X, ntype, order, AWt, Ab, dinv, A0d);
    k_layer<false><<<bL, NT, 0, stream>>>(A0d, rowptr, col, dinv, W1t, b1, (void*)H1d, N);
    k_layer<true><<<bL, NT, 0, stream>>>(H1d, rowptr, col, dinv, W2t, b2, (void*)out, N);
}